// Round 2
// baseline (1369.427 us; speedup 1.0000x reference)
//
#include <hip/hip_runtime.h>
#include <math.h>

#define N_NODES 100000
#define N_EDGES 1600000
#define NBUCK   1563          // ceil(100000/64) buckets of 64 dst nodes
#define NBUCK_P 1568          // row padding (64B-aligned rows)
#define NB_HIST 256           // hist blocks (slice 6250)
#define NB_BIN  64            // bin blocks (slice 25000 = 4 hist slices)

// ws layout (bytes)
#define OFF_FLAG   0x0u
#define OFF_BTOT   0x100u      // int[NBUCK_P]
#define OFF_BBASE  0x2100u     // int[NBUCK+1]
#define OFF_GCHOFF 0x5000u     // int[NB_BIN][NBUCK_P]   (401 KB)
#define OFF_GHIST  0x70000u    // int[NB_HIST][NBUCK_P]  (1.6 MB)
#define OFF_DIS    0x200000u   // float[N_NODES]
#define OFF_HS     0x270000u   // float[N_NODES*128] (51.2 MB)
#define OFF_DUMP   0x3400000u  // int2[<= 2.3M] (24 MB reserved)

// ---- edge dtype detect: int64 edge_index has zero high words ----
__global__ void k_detect(const int* __restrict__ p32, int* __restrict__ flag) {
  __shared__ int nz;
  if (threadIdx.x == 0) nz = 0;
  __syncthreads();
  if (p32[2 * threadIdx.x + 1] != 0) atomicAdd(&nz, 1);
  __syncthreads();
  if (threadIdx.x == 0) *flag = (nz == 0) ? 1 : 0;  // 1 => int64 (stride 2)
}

// per-block bucket histogram of dst
__global__ __launch_bounds__(256) void k_hist(const int* __restrict__ p32,
                                              const int* __restrict__ flag,
                                              int* __restrict__ G_hist) {
  __shared__ int hist[NBUCK];
  const int t = threadIdx.x;
  for (int i = t; i < NBUCK; i += 256) hist[i] = 0;
  __syncthreads();
  const int base = blockIdx.x * 6250;
  const int s = *flag;
  for (int i = 0; i < 25; ++i) {
    int e = base + i * 256 + t;
    if (e < base + 6250) {
      int c = p32[((size_t)(N_EDGES + e)) << s];
      atomicAdd(&hist[c >> 6], 1);
    }
  }
  __syncthreads();
  for (int i = t; i < NBUCK; i += 256) G_hist[blockIdx.x * NBUCK_P + i] = hist[i];
}

// per bucket: sum hist groups of 4 -> 64 bin-chunk sizes, pad to x8, scan
__global__ __launch_bounds__(256) void k_bucket_scan(const int* __restrict__ G_hist,
                                                     int* __restrict__ G_choff,
                                                     int* __restrict__ btot) {
  __shared__ int sm[256];
  const int t = threadIdx.x;
  const int b = blockIdx.x;
  sm[t] = G_hist[t * NBUCK_P + b];
  __syncthreads();
  if (t < 64) {
    int ssum = sm[4 * t] + sm[4 * t + 1] + sm[4 * t + 2] + sm[4 * t + 3];
    int p = (ssum + 7) & ~7;
    int v = p;
    // inclusive scan over 64 lanes (wave 0 only)
    for (int d = 1; d < 64; d <<= 1) {
      int u = __shfl_up(v, d);
      if ((t & 63) >= d) v += u;
    }
    G_choff[t * NBUCK_P + b] = v - p;  // exclusive
    if (t == 63) btot[b] = v;
  }
}

// scan 1563 padded bucket totals -> bbase[0..NBUCK]
__global__ __launch_bounds__(1024) void k_btot_scan(const int* __restrict__ btot,
                                                    int* __restrict__ bbase) {
  __shared__ int sm[1024];
  const int t = threadIdx.x;
  int a = (2 * t < NBUCK) ? btot[2 * t] : 0;
  int bb = (2 * t + 1 < NBUCK) ? btot[2 * t + 1] : 0;
  int pair = a + bb;
  sm[t] = pair;
  __syncthreads();
  for (int off = 1; off < 1024; off <<= 1) {
    int x = (t >= off) ? sm[t - off] : 0;
    __syncthreads();
    sm[t] += x;
    __syncthreads();
  }
  int S = sm[t];  // inclusive pair sum
  if (2 * t <= NBUCK) bbase[2 * t] = S - pair;
  if (2 * t + 1 <= NBUCK) bbase[2 * t + 1] = S - bb;
}

// place (src,dst) records into block-private padded chunks; sentinel tails
__global__ __launch_bounds__(256) void k_bin(const int* __restrict__ p32,
                                             const int* __restrict__ flag,
                                             const int* __restrict__ bbase,
                                             const int* __restrict__ G_choff,
                                             int2* __restrict__ dump) {
  __shared__ int gb[NBUCK];
  __shared__ int cur[NBUCK];
  const int t = threadIdx.x;
  const int blk = blockIdx.x;
  for (int i = t; i < NBUCK; i += 256) {
    gb[i] = bbase[i] + G_choff[blk * NBUCK_P + i];
    cur[i] = 0;
  }
  __syncthreads();
  const int base = blk * 25000;
  const int s = *flag;
  for (int i = 0; i < 98; ++i) {
    int e = base + i * 256 + t;
    if (e < base + 25000) {
      int r = p32[((size_t)e) << s];
      int c = p32[((size_t)(N_EDGES + e)) << s];
      int bk = c >> 6;
      int p = atomicAdd(&cur[bk], 1);
      dump[gb[bk] + p] = make_int2(r, c);
    }
  }
  __syncthreads();
  for (int i = t; i < NBUCK; i += 256) {
    int c0 = cur[i], pe = (c0 + 7) & ~7;
    for (int j = c0; j < pe; ++j) dump[gb[i] + j] = make_int2(0, -1);
  }
}

// degree (incl. nothing) -> dis = rsqrt(deg+1), from the dump (no global atomics)
__global__ __launch_bounds__(256) void k_deg(const int2* __restrict__ dump,
                                             const int* __restrict__ bbase,
                                             float* __restrict__ dis) {
  __shared__ int cnt[64];
  const int t = threadIdx.x;
  const int b = blockIdx.x;
  if (t < 64) cnt[t] = 0;
  __syncthreads();
  const int rb = bbase[b];
  const int m = bbase[b + 1] - rb;
  for (int j = t; j < m; j += 256) {
    int2 rec = dump[rb + j];
    if (rec.y >= 0) atomicAdd(&cnt[rec.y - (b << 6)], 1);
  }
  __syncthreads();
  if (t < 64) {
    int n = (b << 6) + t;
    if (n < N_NODES) dis[n] = rsqrtf((float)cnt[t] + 1.0f);
  }
}

// hs[n] = dis[n] * (x @ W1)[n]   -- 64 rows/block, thread = 4 rows x 8 cols
__global__ __launch_bounds__(256) void k_gemm1(
    const float* __restrict__ x, const float* __restrict__ W,
    const float* __restrict__ dis, float* __restrict__ hs) {
  __shared__ float xs[64][132];
  __shared__ float wsm[128 * 128];
  const int t = threadIdx.x;
  const int row0 = blockIdx.x * 64;
#pragma unroll
  for (int i = 0; i < 16; ++i) {
    int lin = i * 256 + t;
    ((float4*)wsm)[lin] = ((const float4*)W)[lin];
  }
#pragma unroll
  for (int i = 0; i < 8; ++i) {
    int lin = i * 256 + t;
    int r = lin >> 5, c4 = lin & 31;
    int gr = row0 + r;
    float4 v = make_float4(0.f, 0.f, 0.f, 0.f);
    if (gr < N_NODES) v = *(const float4*)(x + (size_t)gr * 128 + c4 * 4);
    xs[r][c4 * 4 + 0] = v.x; xs[r][c4 * 4 + 1] = v.y;
    xs[r][c4 * 4 + 2] = v.z; xs[r][c4 * 4 + 3] = v.w;
  }
  __syncthreads();
  const int ty = t >> 4, tx = t & 15;
  float acc[4][8];
#pragma unroll
  for (int i = 0; i < 4; ++i)
#pragma unroll
    for (int j = 0; j < 8; ++j) acc[i][j] = 0.f;
#pragma unroll 4
  for (int k = 0; k < 128; ++k) {
    float xv[4];
#pragma unroll
    for (int i = 0; i < 4; ++i) xv[i] = xs[ty * 4 + i][k];
    float4 wa = *(const float4*)&wsm[k * 128 + tx * 8];
    float4 wb = *(const float4*)&wsm[k * 128 + tx * 8 + 4];
    float wv[8] = {wa.x, wa.y, wa.z, wa.w, wb.x, wb.y, wb.z, wb.w};
#pragma unroll
    for (int i = 0; i < 4; ++i)
#pragma unroll
      for (int j = 0; j < 8; ++j) acc[i][j] = fmaf(xv[i], wv[j], acc[i][j]);
  }
#pragma unroll
  for (int i = 0; i < 4; ++i) {
    int r = row0 + ty * 4 + i;
    if (r >= N_NODES) continue;
    float d = dis[r];
    float4 o0 = make_float4(acc[i][0] * d, acc[i][1] * d, acc[i][2] * d, acc[i][3] * d);
    float4 o1 = make_float4(acc[i][4] * d, acc[i][5] * d, acc[i][6] * d, acc[i][7] * d);
    *(float4*)(hs + (size_t)r * 128 + tx * 8) = o0;
    *(float4*)(hs + (size_t)r * 128 + tx * 8 + 4) = o1;
  }
}

// bucket aggregate in LDS + fused Linear + log_softmax
__global__ __launch_bounds__(256) void k_agg(
    const float* __restrict__ hs, const int2* __restrict__ dump,
    const int* __restrict__ bbase, const float* __restrict__ dis,
    const float* __restrict__ b1, const float* __restrict__ linW,
    const float* __restrict__ linb, float* __restrict__ out) {
  __shared__ float accs[64 * 129];   // stride 129: conflict-free scalar adds
  __shared__ float dis_s[64];
  __shared__ float b1s[128];
  const int t = threadIdx.x;
  const int b = blockIdx.x;
  const int n0 = b << 6;
  // init acc rows with self-loop term hs[n]
  for (int idx = t; idx < 64 * 128; idx += 256) {
    int r = idx >> 7, k = idx & 127;
    int n = n0 + r;
    accs[r * 129 + k] = (n < N_NODES) ? hs[(size_t)n * 128 + k] : 0.f;
  }
  if (t < 64) {
    int n = n0 + t;
    dis_s[t] = (n < N_NODES) ? dis[n] : 0.f;
  }
  if (t >= 128 && t < 256) b1s[t - 128] = b1[t - 128];
  __syncthreads();

  const int rb = bbase[b];
  const int m = bbase[b + 1] - rb;
  const int wv = t >> 6, half = (t >> 5) & 1, l = t & 31;
  const int hw = wv * 2 + half;
  for (int j = hw; j < m; j += 16) {
    int2 rec0 = dump[rb + j];
    int j2 = j + 8;
    int2 rec1 = (j2 < m) ? dump[rb + j2] : make_int2(0, -1);
    bool k0 = rec0.y >= 0, k1 = rec1.y >= 0;
    float a0 = 0.f, a1 = 0.f, a2 = 0.f, a3 = 0.f;
    float c0 = 0.f, c1 = 0.f, c2 = 0.f, c3 = 0.f;
    if (k0) {
      const float* r0 = hs + (size_t)rec0.x * 128 + l;
      a0 = r0[0]; a1 = r0[32]; a2 = r0[64]; a3 = r0[96];
    }
    if (k1) {
      const float* r1 = hs + (size_t)rec1.x * 128 + l;
      c0 = r1[0]; c1 = r1[32]; c2 = r1[64]; c3 = r1[96];
    }
    if (k0) {
      float* ar = accs + (rec0.y - n0) * 129 + l;
      atomicAdd(ar, a0); atomicAdd(ar + 32, a1);
      atomicAdd(ar + 64, a2); atomicAdd(ar + 96, a3);
    }
    if (k1) {
      float* ar = accs + (rec1.y - n0) * 129 + l;
      atomicAdd(ar, c0); atomicAdd(ar + 32, c1);
      atomicAdd(ar + 64, c2); atomicAdd(ar + 96, c3);
    }
  }
  __syncthreads();

  // final: node = t>>2 (0..63), 10 classes per lane-quadrant
  const int node = t >> 2;
  const int cc = (t & 3) * 10;
  const float d = dis_s[node];
  float lg[10];
#pragma unroll
  for (int j = 0; j < 10; ++j) lg[j] = linb[cc + j];
  for (int k = 0; k < 128; ++k) {
    float a = fmaxf(fmaf(d, accs[node * 129 + k], b1s[k]), 0.f);
    const float* wr = linW + k * 40 + cc;
#pragma unroll
    for (int j = 0; j < 10; ++j) lg[j] = fmaf(a, wr[j], lg[j]);
  }
  float mx = lg[0];
#pragma unroll
  for (int j = 1; j < 10; ++j) mx = fmaxf(mx, lg[j]);
  mx = fmaxf(mx, __shfl_xor(mx, 1));
  mx = fmaxf(mx, __shfl_xor(mx, 2));
  float ssum = 0.f;
#pragma unroll
  for (int j = 0; j < 10; ++j) ssum += expf(lg[j] - mx);
  ssum += __shfl_xor(ssum, 1);
  ssum += __shfl_xor(ssum, 2);
  float lse = mx + logf(ssum);
  int n = n0 + node;
  if (n < N_NODES) {
#pragma unroll
    for (int j = 0; j < 10; ++j) out[(size_t)n * 40 + cc + j] = lg[j] - lse;
  }
}

extern "C" void kernel_launch(void* const* d_in, const int* in_sizes, int n_in,
                              void* d_out, int out_size, void* d_ws, size_t ws_size,
                              hipStream_t stream) {
  const float* x    = (const float*)d_in[0];
  const int*   ei   = (const int*)d_in[1];
  const float* W1   = (const float*)d_in[2];
  const float* b1   = (const float*)d_in[3];
  const float* linW = (const float*)d_in[4];
  const float* linb = (const float*)d_in[5];
  float* out = (float*)d_out;
  char* ws = (char*)d_ws;

  int*   flag   = (int*)(ws + OFF_FLAG);
  int*   btot   = (int*)(ws + OFF_BTOT);
  int*   bbase  = (int*)(ws + OFF_BBASE);
  int*   gchoff = (int*)(ws + OFF_GCHOFF);
  int*   ghist  = (int*)(ws + OFF_GHIST);
  float* dis    = (float*)(ws + OFF_DIS);
  float* hs     = (float*)(ws + OFF_HS);
  int2*  dump   = (int2*)(ws + OFF_DUMP);

  k_detect<<<1, 256, 0, stream>>>(ei, flag);
  k_hist<<<NB_HIST, 256, 0, stream>>>(ei, flag, ghist);
  k_bucket_scan<<<NBUCK, 256, 0, stream>>>(ghist, gchoff, btot);
  k_btot_scan<<<1, 1024, 0, stream>>>(btot, bbase);
  k_bin<<<NB_BIN, 256, 0, stream>>>(ei, flag, bbase, gchoff, dump);
  k_deg<<<NBUCK, 256, 0, stream>>>(dump, bbase, dis);
  k_gemm1<<<NBUCK, 256, 0, stream>>>(x, W1, dis, hs);
  k_agg<<<NBUCK, 256, 0, stream>>>(hs, dump, bbase, dis, b1, linW, linb, out);
}

// Round 4
// 332.934 us; speedup vs baseline: 4.1132x; 4.1132x over previous
//
#include <hip/hip_runtime.h>
#include <math.h>

#define N_NODES 100000
#define N_EDGES 1600000
#define NBUCK   1563          // ceil(100000/64) buckets of 64 dst nodes
#define NBUCK_P 1568          // padded row length for hist tables
#define NB_HIST 256           // hist blocks (slice 6250)
#define NB_BIN  64            // bin blocks (slice 25000)

// ws layout (bytes). acc aliases {ghist,gchoff,dump}: dead before k_agg writes.
#define OFF_FLAG   0x0u
#define OFF_BTOT   0x1000u     // int[NBUCK_P]   padded bucket totals
#define OFF_UBTOT  0x3000u     // int[NBUCK_P]   unpadded bucket totals
#define OFF_BBASE  0x5000u     // int[NBUCK+1]   padded scan (dump base)
#define OFF_CBASE  0x7000u     // int[NBUCK+1]   compact scan (srcs base)
#define OFF_DIS    0x9000u     // float[N_NODES]
#define OFF_CNT    0x70000u    // int[N_NODES]
#define OFF_START  0xE0000u    // int[N_NODES]
#define OFF_SRCS   0x150000u   // int[N_EDGES]  (compact: exactly <=1.6M)
#define OFF_HS     0x780000u   // float[N_NODES*128]  (ends 0x3854000)
#define OFF_GHIST  0x3980000u  // int[NB_HIST*NBUCK_P]
#define OFF_GCHOFF 0x3B10000u  // int[NB_BIN*NBUCK_P]
#define OFF_DUMP   0x3B80000u  // int2[<=2.35M]  (ends < 0x4D70000)
#define OFF_ACC    0x3980000u  // float[N_NODES*128] aliases binning scratch

// ---- edge dtype detect: int64 edge_index has zero high words ----
__global__ void k_detect(const int* __restrict__ p32, int* __restrict__ flag) {
  __shared__ int nz;
  if (threadIdx.x == 0) nz = 0;
  __syncthreads();
  if (p32[2 * threadIdx.x + 1] != 0) atomicAdd(&nz, 1);
  __syncthreads();
  if (threadIdx.x == 0) *flag = (nz == 0) ? 1 : 0;  // 1 => int64 (stride 2)
}

// per-block bucket histogram of dst
__global__ __launch_bounds__(256) void k_hist(const int* __restrict__ p32,
                                              const int* __restrict__ flag,
                                              int* __restrict__ G_hist) {
  __shared__ int hist[NBUCK];
  const int t = threadIdx.x;
  for (int i = t; i < NBUCK; i += 256) hist[i] = 0;
  __syncthreads();
  const int base = blockIdx.x * 6250;
  const int s = *flag;
  for (int i = 0; i < 25; ++i) {
    int e = base + i * 256 + t;
    if (e < base + 6250) {
      int c = p32[((size_t)(N_EDGES + e)) << s];
      atomicAdd(&hist[c >> 6], 1);
    }
  }
  __syncthreads();
  for (int i = t; i < NBUCK; i += 256) G_hist[blockIdx.x * NBUCK_P + i] = hist[i];
}

// per bucket: 64 bin-chunk sizes (sum hist groups of 4), pad to x8, scan.
// Emits padded chunk offsets + padded total (dump) and unpadded total (CSR).
__global__ __launch_bounds__(256) void k_bucket_scan(const int* __restrict__ G_hist,
                                                     int* __restrict__ G_choff,
                                                     int* __restrict__ btot,
                                                     int* __restrict__ ubtot) {
  __shared__ int sm[256];
  const int t = threadIdx.x;
  const int b = blockIdx.x;
  sm[t] = G_hist[t * NBUCK_P + b];
  __syncthreads();
  if (t < 64) {
    int ssum = sm[4 * t] + sm[4 * t + 1] + sm[4 * t + 2] + sm[4 * t + 3];
    int p = (ssum + 7) & ~7;
    int v = p;
    int u = ssum;
    for (int d = 1; d < 64; d <<= 1) {
      int vv = __shfl_up(v, d);
      int uu = __shfl_up(u, d);
      if ((t & 63) >= d) { v += vv; u += uu; }
    }
    G_choff[t * NBUCK_P + b] = v - p;  // exclusive padded offset within bucket
    if (t == 63) { btot[b] = v; ubtot[b] = u; }
  }
}

// scan 1563 totals -> base[0..NBUCK] (exclusive); generic, 1 block
__global__ __launch_bounds__(1024) void k_scan_tot(const int* __restrict__ tot,
                                                   int* __restrict__ base) {
  __shared__ int sm[1024];
  const int t = threadIdx.x;
  int a = (2 * t < NBUCK) ? tot[2 * t] : 0;
  int bb = (2 * t + 1 < NBUCK) ? tot[2 * t + 1] : 0;
  int pair = a + bb;
  sm[t] = pair;
  __syncthreads();
  for (int off = 1; off < 1024; off <<= 1) {
    int x = (t >= off) ? sm[t - off] : 0;
    __syncthreads();
    sm[t] += x;
    __syncthreads();
  }
  int S = sm[t];
  if (2 * t <= NBUCK) base[2 * t] = S - pair;
  if (2 * t + 1 <= NBUCK) base[2 * t + 1] = S - bb;
}

// place (src,dst) records into block-private padded chunks; sentinel tails
__global__ __launch_bounds__(256) void k_bin(const int* __restrict__ p32,
                                             const int* __restrict__ flag,
                                             const int* __restrict__ bbase,
                                             const int* __restrict__ G_choff,
                                             int2* __restrict__ dump) {
  __shared__ int gb[NBUCK];
  __shared__ int cur[NBUCK];
  const int t = threadIdx.x;
  const int blk = blockIdx.x;
  for (int i = t; i < NBUCK; i += 256) {
    gb[i] = bbase[i] + G_choff[blk * NBUCK_P + i];
    cur[i] = 0;
  }
  __syncthreads();
  const int base = blk * 25000;
  const int s = *flag;
  for (int i = 0; i < 98; ++i) {
    int e = base + i * 256 + t;
    if (e < base + 25000) {
      int r = p32[((size_t)e) << s];
      int c = p32[((size_t)(N_EDGES + e)) << s];
      int bk = c >> 6;
      int p = atomicAdd(&cur[bk], 1);
      dump[gb[bk] + p] = make_int2(r, c);
    }
  }
  __syncthreads();
  for (int i = t; i < NBUCK; i += 256) {
    int c0 = cur[i], pe = (c0 + 7) & ~7;
    for (int j = c0; j < pe; ++j) dump[gb[i] + j] = make_int2(0, -1);
  }
}

// per bucket: dump chunk -> per-node CSR at COMPACT offsets + deg/dis
__global__ __launch_bounds__(256) void k_csr(const int2* __restrict__ dump,
                                             const int* __restrict__ bbase,
                                             const int* __restrict__ cbase,
                                             int* __restrict__ srcs,
                                             int* __restrict__ startp,
                                             int* __restrict__ cnt,
                                             float* __restrict__ dis) {
  __shared__ int cnt_s[64];
  __shared__ int off_s[64];
  __shared__ int cur_s[64];
  __shared__ int stage[3072];
  const int t = threadIdx.x;
  const int b = blockIdx.x;
  if (t < 64) cnt_s[t] = 0;
  __syncthreads();
  const int rb = bbase[b];          // padded dump base (read)
  const int m = bbase[b + 1] - rb;  // padded record count (incl sentinels)
  const int cb = cbase[b];          // compact srcs base (write)
  for (int j = t; j < m; j += 256) {
    int2 rec = dump[rb + j];
    if (rec.y >= 0) atomicAdd(&cnt_s[rec.y & 63], 1);
  }
  __syncthreads();
  if (t < 64) {
    int v = cnt_s[t];
    int sv = v;
    for (int d = 1; d < 64; d <<= 1) {
      int u = __shfl_up(sv, d);
      if (t >= d) sv += u;
    }
    off_s[t] = sv - v;
    cur_s[t] = sv - v;
  }
  __syncthreads();
  for (int j = t; j < m; j += 256) {
    int2 rec = dump[rb + j];
    if (rec.y >= 0) {
      int p = atomicAdd(&cur_s[rec.y & 63], 1);
      stage[p] = rec.x;
    }
  }
  __syncthreads();
  const int total = off_s[63] + cnt_s[63];
  for (int j = t; j < total; j += 256) srcs[cb + j] = stage[j];
  if (t < 64) {
    int n = (b << 6) + t;
    if (n < N_NODES) {
      cnt[n] = cnt_s[t];
      startp[n] = cb + off_s[t];
      dis[n] = rsqrtf((float)cnt_s[t] + 1.0f);
    }
  }
}

// hs[n] = dis[n] * (x @ W1)[n]   -- 64 rows/block, thread = 4 rows x 8 cols
__global__ __launch_bounds__(256) void k_gemm1(
    const float* __restrict__ x, const float* __restrict__ W,
    const float* __restrict__ dis, float* __restrict__ hs) {
  __shared__ float xs[64][132];
  __shared__ float wsm[128 * 128];
  const int t = threadIdx.x;
  const int row0 = blockIdx.x * 64;
#pragma unroll
  for (int i = 0; i < 16; ++i) {
    int lin = i * 256 + t;
    ((float4*)wsm)[lin] = ((const float4*)W)[lin];
  }
#pragma unroll
  for (int i = 0; i < 8; ++i) {
    int lin = i * 256 + t;
    int r = lin >> 5, c4 = lin & 31;
    int gr = row0 + r;
    float4 v = make_float4(0.f, 0.f, 0.f, 0.f);
    if (gr < N_NODES) v = *(const float4*)(x + (size_t)gr * 128 + c4 * 4);
    xs[r][c4 * 4 + 0] = v.x; xs[r][c4 * 4 + 1] = v.y;
    xs[r][c4 * 4 + 2] = v.z; xs[r][c4 * 4 + 3] = v.w;
  }
  __syncthreads();
  const int ty = t >> 4, tx = t & 15;
  float acc[4][8];
#pragma unroll
  for (int i = 0; i < 4; ++i)
#pragma unroll
    for (int j = 0; j < 8; ++j) acc[i][j] = 0.f;
#pragma unroll 4
  for (int k = 0; k < 128; ++k) {
    float xv[4];
#pragma unroll
    for (int i = 0; i < 4; ++i) xv[i] = xs[ty * 4 + i][k];
    float4 wa = *(const float4*)&wsm[k * 128 + tx * 8];
    float4 wb = *(const float4*)&wsm[k * 128 + tx * 8 + 4];
    float wv[8] = {wa.x, wa.y, wa.z, wa.w, wb.x, wb.y, wb.z, wb.w};
#pragma unroll
    for (int i = 0; i < 4; ++i)
#pragma unroll
      for (int j = 0; j < 8; ++j) acc[i][j] = fmaf(xv[i], wv[j], acc[i][j]);
  }
#pragma unroll
  for (int i = 0; i < 4; ++i) {
    int r = row0 + ty * 4 + i;
    if (r >= N_NODES) continue;
    float d = dis[r];
    float4 o0 = make_float4(acc[i][0] * d, acc[i][1] * d, acc[i][2] * d, acc[i][3] * d);
    float4 o1 = make_float4(acc[i][4] * d, acc[i][5] * d, acc[i][6] * d, acc[i][7] * d);
    *(float4*)(hs + (size_t)r * 128 + tx * 8) = o0;
    *(float4*)(hs + (size_t)r * 128 + tx * 8 + 4) = o1;
  }
}

// acc[n] = dis[n] * (hs[n] + sum_in hs[src]) + b1   -- 32 lanes/node, 4x unroll
__global__ __launch_bounds__(256) void k_agg(
    const float* __restrict__ hs, const int* __restrict__ startp,
    const int* __restrict__ cnt, const int* __restrict__ srcs,
    const float* __restrict__ dis, const float* __restrict__ b1,
    float* __restrict__ acc) {
  const int t = threadIdx.x;
  const int g = t >> 5, lane = t & 31;
  const int n = blockIdx.x * 8 + g;
  if (n >= N_NODES) return;
  float4 sum = *(const float4*)(hs + (size_t)n * 128 + lane * 4);  // self-loop
  const int s0 = startp[n];
  const int e0 = s0 + cnt[n];
  int j = s0;
  for (; j + 4 <= e0; j += 4) {
    int i0 = srcs[j], i1 = srcs[j + 1], i2 = srcs[j + 2], i3 = srcs[j + 3];
    float4 v0 = *(const float4*)(hs + (size_t)i0 * 128 + lane * 4);
    float4 v1 = *(const float4*)(hs + (size_t)i1 * 128 + lane * 4);
    float4 v2 = *(const float4*)(hs + (size_t)i2 * 128 + lane * 4);
    float4 v3 = *(const float4*)(hs + (size_t)i3 * 128 + lane * 4);
    sum.x += (v0.x + v1.x) + (v2.x + v3.x);
    sum.y += (v0.y + v1.y) + (v2.y + v3.y);
    sum.z += (v0.z + v1.z) + (v2.z + v3.z);
    sum.w += (v0.w + v1.w) + (v2.w + v3.w);
  }
  for (; j < e0; ++j) {
    int src = srcs[j];
    float4 v = *(const float4*)(hs + (size_t)src * 128 + lane * 4);
    sum.x += v.x; sum.y += v.y; sum.z += v.z; sum.w += v.w;
  }
  float d = dis[n];
  float4 b = *(const float4*)(b1 + lane * 4);
  float4 o = make_float4(fmaf(d, sum.x, b.x), fmaf(d, sum.y, b.y),
                         fmaf(d, sum.z, b.z), fmaf(d, sum.w, b.w));
  *(float4*)(acc + (size_t)n * 128 + lane * 4) = o;
}

// out[n] = log_softmax(relu(acc[n]) @ linW + linb)   -- 4 lanes/node
__global__ __launch_bounds__(256) void k_final(
    const float* __restrict__ acc, const float* __restrict__ linW,
    const float* __restrict__ linb, float* __restrict__ out) {
  __shared__ float vs[64][132];
  __shared__ float wl[128 * 40];
  __shared__ float lb[40];
  const int t = threadIdx.x;
  const int n0 = blockIdx.x * 64;
#pragma unroll
  for (int i = 0; i < 5; ++i) {
    int lin = i * 256 + t;
    ((float4*)wl)[lin] = ((const float4*)linW)[lin];
  }
  if (t < 40) lb[t] = linb[t];
#pragma unroll
  for (int i = 0; i < 8; ++i) {
    int lin = i * 256 + t;
    int r = lin >> 5, c4 = lin & 31;
    int n = n0 + r;
    float4 v = make_float4(0.f, 0.f, 0.f, 0.f);
    if (n < N_NODES) {
      v = *(const float4*)(acc + (size_t)n * 128 + c4 * 4);
      v.x = fmaxf(v.x, 0.f); v.y = fmaxf(v.y, 0.f);
      v.z = fmaxf(v.z, 0.f); v.w = fmaxf(v.w, 0.f);
    }
    vs[r][c4 * 4 + 0] = v.x; vs[r][c4 * 4 + 1] = v.y;
    vs[r][c4 * 4 + 2] = v.z; vs[r][c4 * 4 + 3] = v.w;
  }
  __syncthreads();
  const int nl = t >> 2, l4 = t & 3;
  const int n = n0 + nl;
  if (n >= N_NODES) return;
  float lg[10];
#pragma unroll
  for (int j = 0; j < 10; ++j) lg[j] = lb[l4 * 10 + j];
  for (int k = 0; k < 128; ++k) {
    float vk = vs[nl][k];
#pragma unroll
    for (int j = 0; j < 10; ++j) lg[j] = fmaf(vk, wl[k * 40 + l4 * 10 + j], lg[j]);
  }
  float m = lg[0];
#pragma unroll
  for (int j = 1; j < 10; ++j) m = fmaxf(m, lg[j]);
  m = fmaxf(m, __shfl_xor(m, 1));
  m = fmaxf(m, __shfl_xor(m, 2));
  float s = 0.f;
#pragma unroll
  for (int j = 0; j < 10; ++j) s += expf(lg[j] - m);
  s += __shfl_xor(s, 1);
  s += __shfl_xor(s, 2);
  float lse = m + logf(s);
#pragma unroll
  for (int j = 0; j < 10; ++j) out[(size_t)n * 40 + l4 * 10 + j] = lg[j] - lse;
}

extern "C" void kernel_launch(void* const* d_in, const int* in_sizes, int n_in,
                              void* d_out, int out_size, void* d_ws, size_t ws_size,
                              hipStream_t stream) {
  const float* x    = (const float*)d_in[0];
  const int*   ei   = (const int*)d_in[1];
  const float* W1   = (const float*)d_in[2];
  const float* b1   = (const float*)d_in[3];
  const float* linW = (const float*)d_in[4];
  const float* linb = (const float*)d_in[5];
  float* out = (float*)d_out;
  char* ws = (char*)d_ws;

  int*   flag   = (int*)(ws + OFF_FLAG);
  int*   btot   = (int*)(ws + OFF_BTOT);
  int*   ubtot  = (int*)(ws + OFF_UBTOT);
  int*   bbase  = (int*)(ws + OFF_BBASE);
  int*   cbase  = (int*)(ws + OFF_CBASE);
  float* dis    = (float*)(ws + OFF_DIS);
  int*   cnt    = (int*)(ws + OFF_CNT);
  int*   startp = (int*)(ws + OFF_START);
  int*   srcs   = (int*)(ws + OFF_SRCS);
  float* hs     = (float*)(ws + OFF_HS);
  int*   ghist  = (int*)(ws + OFF_GHIST);
  int*   gchoff = (int*)(ws + OFF_GCHOFF);
  int2*  dump   = (int2*)(ws + OFF_DUMP);
  float* acc    = (float*)(ws + OFF_ACC);

  k_detect<<<1, 256, 0, stream>>>(ei, flag);
  k_hist<<<NB_HIST, 256, 0, stream>>>(ei, flag, ghist);
  k_bucket_scan<<<NBUCK, 256, 0, stream>>>(ghist, gchoff, btot, ubtot);
  k_scan_tot<<<1, 1024, 0, stream>>>(btot, bbase);
  k_scan_tot<<<1, 1024, 0, stream>>>(ubtot, cbase);
  k_bin<<<NB_BIN, 256, 0, stream>>>(ei, flag, bbase, gchoff, dump);
  k_csr<<<NBUCK, 256, 0, stream>>>(dump, bbase, cbase, srcs, startp, cnt, dis);
  k_gemm1<<<NBUCK, 256, 0, stream>>>(x, W1, dis, hs);
  k_agg<<<(N_NODES + 7) / 8, 256, 0, stream>>>(hs, startp, cnt, srcs, dis, b1, acc);
  k_final<<<NBUCK, 256, 0, stream>>>(acc, linW, linb, out);
}

// Round 5
// 269.908 us; speedup vs baseline: 5.0737x; 1.2335x over previous
//
#include <hip/hip_runtime.h>
#include <hip/hip_fp16.h>
#include <math.h>

#define N_NODES 100000
#define N_EDGES 1600000
#define NBUCK   1563          // ceil(100000/64) buckets of 64 dst nodes
#define NBUCK_P 1568          // padded row length for hist tables
#define NB_HIST 256           // hist blocks (slice 6250)
#define NB_BIN  64            // bin blocks (slice 25000)

// ws layout (bytes). acc aliases {ghist,gchoff,dump}: dead before k_agg writes.
#define OFF_FLAG   0x0u
#define OFF_BTOT   0x1000u     // int[NBUCK_P]   padded bucket totals
#define OFF_UBTOT  0x3000u     // int[NBUCK_P]   unpadded bucket totals
#define OFF_BBASE  0x5000u     // int[NBUCK+1]   padded scan (dump base)
#define OFF_CBASE  0x7000u     // int[NBUCK+1]   compact scan (srcs base)
#define OFF_DIS    0x9000u     // float[N_NODES]
#define OFF_CNT    0x70000u    // int[N_NODES]
#define OFF_START  0xE0000u    // int[N_NODES]
#define OFF_SRCS   0x150000u   // int[N_EDGES]
#define OFF_HS     0x780000u   // __half[N_NODES*128] (25.6 MB, ends < 0x2100000)
#define OFF_GHIST  0x3980000u  // int[NB_HIST*NBUCK_P]
#define OFF_GCHOFF 0x3B10000u  // int[NB_BIN*NBUCK_P]
#define OFF_DUMP   0x3B80000u  // int2[<=2.35M]
#define OFF_ACC    0x3980000u  // __half[N_NODES*128] aliases binning scratch

// ---- edge dtype detect: int64 edge_index has zero high words ----
__global__ void k_detect(const int* __restrict__ p32, int* __restrict__ flag) {
  __shared__ int nz;
  if (threadIdx.x == 0) nz = 0;
  __syncthreads();
  if (p32[2 * threadIdx.x + 1] != 0) atomicAdd(&nz, 1);
  __syncthreads();
  if (threadIdx.x == 0) *flag = (nz == 0) ? 1 : 0;  // 1 => int64 (stride 2)
}

// per-block bucket histogram of dst
__global__ __launch_bounds__(256) void k_hist(const int* __restrict__ p32,
                                              const int* __restrict__ flag,
                                              int* __restrict__ G_hist) {
  __shared__ int hist[NBUCK];
  const int t = threadIdx.x;
  for (int i = t; i < NBUCK; i += 256) hist[i] = 0;
  __syncthreads();
  const int base = blockIdx.x * 6250;
  const int s = *flag;
  for (int i = 0; i < 25; ++i) {
    int e = base + i * 256 + t;
    if (e < base + 6250) {
      int c = p32[((size_t)(N_EDGES + e)) << s];
      atomicAdd(&hist[c >> 6], 1);
    }
  }
  __syncthreads();
  for (int i = t; i < NBUCK; i += 256) G_hist[blockIdx.x * NBUCK_P + i] = hist[i];
}

// per bucket: 64 bin-chunk sizes (sum hist groups of 4), pad to x8, scan.
__global__ __launch_bounds__(256) void k_bucket_scan(const int* __restrict__ G_hist,
                                                     int* __restrict__ G_choff,
                                                     int* __restrict__ btot,
                                                     int* __restrict__ ubtot) {
  __shared__ int sm[256];
  const int t = threadIdx.x;
  const int b = blockIdx.x;
  sm[t] = G_hist[t * NBUCK_P + b];
  __syncthreads();
  if (t < 64) {
    int ssum = sm[4 * t] + sm[4 * t + 1] + sm[4 * t + 2] + sm[4 * t + 3];
    int p = (ssum + 7) & ~7;
    int v = p;
    int u = ssum;
    for (int d = 1; d < 64; d <<= 1) {
      int vv = __shfl_up(v, d);
      int uu = __shfl_up(u, d);
      if ((t & 63) >= d) { v += vv; u += uu; }
    }
    G_choff[t * NBUCK_P + b] = v - p;  // exclusive padded offset within bucket
    if (t == 63) { btot[b] = v; ubtot[b] = u; }
  }
}

// scan 1563 totals -> base[0..NBUCK] (exclusive); generic, 1 block
__global__ __launch_bounds__(1024) void k_scan_tot(const int* __restrict__ tot,
                                                   int* __restrict__ base) {
  __shared__ int sm[1024];
  const int t = threadIdx.x;
  int a = (2 * t < NBUCK) ? tot[2 * t] : 0;
  int bb = (2 * t + 1 < NBUCK) ? tot[2 * t + 1] : 0;
  int pair = a + bb;
  sm[t] = pair;
  __syncthreads();
  for (int off = 1; off < 1024; off <<= 1) {
    int x = (t >= off) ? sm[t - off] : 0;
    __syncthreads();
    sm[t] += x;
    __syncthreads();
  }
  int S = sm[t];
  if (2 * t <= NBUCK) base[2 * t] = S - pair;
  if (2 * t + 1 <= NBUCK) base[2 * t + 1] = S - bb;
}

// place (src,dst) records into block-private padded chunks; sentinel tails
__global__ __launch_bounds__(256) void k_bin(const int* __restrict__ p32,
                                             const int* __restrict__ flag,
                                             const int* __restrict__ bbase,
                                             const int* __restrict__ G_choff,
                                             int2* __restrict__ dump) {
  __shared__ int gb[NBUCK];
  __shared__ int cur[NBUCK];
  const int t = threadIdx.x;
  const int blk = blockIdx.x;
  for (int i = t; i < NBUCK; i += 256) {
    gb[i] = bbase[i] + G_choff[blk * NBUCK_P + i];
    cur[i] = 0;
  }
  __syncthreads();
  const int base = blk * 25000;
  const int s = *flag;
  for (int i = 0; i < 98; ++i) {
    int e = base + i * 256 + t;
    if (e < base + 25000) {
      int r = p32[((size_t)e) << s];
      int c = p32[((size_t)(N_EDGES + e)) << s];
      int bk = c >> 6;
      int p = atomicAdd(&cur[bk], 1);
      dump[gb[bk] + p] = make_int2(r, c);
    }
  }
  __syncthreads();
  for (int i = t; i < NBUCK; i += 256) {
    int c0 = cur[i], pe = (c0 + 7) & ~7;
    for (int j = c0; j < pe; ++j) dump[gb[i] + j] = make_int2(0, -1);
  }
}

// per bucket: dump chunk -> per-node CSR at COMPACT offsets + deg/dis
__global__ __launch_bounds__(256) void k_csr(const int2* __restrict__ dump,
                                             const int* __restrict__ bbase,
                                             const int* __restrict__ cbase,
                                             int* __restrict__ srcs,
                                             int* __restrict__ startp,
                                             int* __restrict__ cnt,
                                             float* __restrict__ dis) {
  __shared__ int cnt_s[64];
  __shared__ int off_s[64];
  __shared__ int cur_s[64];
  __shared__ int stage[3072];
  const int t = threadIdx.x;
  const int b = blockIdx.x;
  if (t < 64) cnt_s[t] = 0;
  __syncthreads();
  const int rb = bbase[b];
  const int m = bbase[b + 1] - rb;
  const int cb = cbase[b];
  for (int j = t; j < m; j += 256) {
    int2 rec = dump[rb + j];
    if (rec.y >= 0) atomicAdd(&cnt_s[rec.y & 63], 1);
  }
  __syncthreads();
  if (t < 64) {
    int v = cnt_s[t];
    int sv = v;
    for (int d = 1; d < 64; d <<= 1) {
      int u = __shfl_up(sv, d);
      if (t >= d) sv += u;
    }
    off_s[t] = sv - v;
    cur_s[t] = sv - v;
  }
  __syncthreads();
  for (int j = t; j < m; j += 256) {
    int2 rec = dump[rb + j];
    if (rec.y >= 0) {
      int p = atomicAdd(&cur_s[rec.y & 63], 1);
      stage[p] = rec.x;
    }
  }
  __syncthreads();
  const int total = off_s[63] + cnt_s[63];
  for (int j = t; j < total; j += 256) srcs[cb + j] = stage[j];
  if (t < 64) {
    int n = (b << 6) + t;
    if (n < N_NODES) {
      cnt[n] = cnt_s[t];
      startp[n] = cb + off_s[t];
      dis[n] = rsqrtf((float)cnt_s[t] + 1.0f);
    }
  }
}

// hs[n] = fp16( dis[n] * (x @ W1)[n] )  -- 64 rows/block, thread = 4 rows x 8 cols
__global__ __launch_bounds__(256) void k_gemm1(
    const float* __restrict__ x, const float* __restrict__ W,
    const float* __restrict__ dis, __half* __restrict__ hs) {
  __shared__ float xs[64][132];
  __shared__ float wsm[128 * 128];
  const int t = threadIdx.x;
  const int row0 = blockIdx.x * 64;
#pragma unroll
  for (int i = 0; i < 16; ++i) {
    int lin = i * 256 + t;
    ((float4*)wsm)[lin] = ((const float4*)W)[lin];
  }
#pragma unroll
  for (int i = 0; i < 8; ++i) {
    int lin = i * 256 + t;
    int r = lin >> 5, c4 = lin & 31;
    int gr = row0 + r;
    float4 v = make_float4(0.f, 0.f, 0.f, 0.f);
    if (gr < N_NODES) v = *(const float4*)(x + (size_t)gr * 128 + c4 * 4);
    xs[r][c4 * 4 + 0] = v.x; xs[r][c4 * 4 + 1] = v.y;
    xs[r][c4 * 4 + 2] = v.z; xs[r][c4 * 4 + 3] = v.w;
  }
  __syncthreads();
  const int ty = t >> 4, tx = t & 15;
  float acc[4][8];
#pragma unroll
  for (int i = 0; i < 4; ++i)
#pragma unroll
    for (int j = 0; j < 8; ++j) acc[i][j] = 0.f;
#pragma unroll 4
  for (int k = 0; k < 128; ++k) {
    float xv[4];
#pragma unroll
    for (int i = 0; i < 4; ++i) xv[i] = xs[ty * 4 + i][k];
    float4 wa = *(const float4*)&wsm[k * 128 + tx * 8];
    float4 wb = *(const float4*)&wsm[k * 128 + tx * 8 + 4];
    float wv[8] = {wa.x, wa.y, wa.z, wa.w, wb.x, wb.y, wb.z, wb.w};
#pragma unroll
    for (int i = 0; i < 4; ++i)
#pragma unroll
      for (int j = 0; j < 8; ++j) acc[i][j] = fmaf(xv[i], wv[j], acc[i][j]);
  }
#pragma unroll
  for (int i = 0; i < 4; ++i) {
    int r = row0 + ty * 4 + i;
    if (r >= N_NODES) continue;
    float d = dis[r];
    union { __half2 h[4]; int4 v; } u;
    u.h[0] = __floats2half2_rn(acc[i][0] * d, acc[i][1] * d);
    u.h[1] = __floats2half2_rn(acc[i][2] * d, acc[i][3] * d);
    u.h[2] = __floats2half2_rn(acc[i][4] * d, acc[i][5] * d);
    u.h[3] = __floats2half2_rn(acc[i][6] * d, acc[i][7] * d);
    *(int4*)(hs + (size_t)r * 128 + tx * 8) = u.v;  // 16B aligned
  }
}

// acc[n] = fp16( dis[n]*(hs[n] + sum_in hs[src]) + b1 )  -- 32 lanes/node
__global__ __launch_bounds__(256) void k_agg(
    const __half* __restrict__ hs, const int* __restrict__ startp,
    const int* __restrict__ cnt, const int* __restrict__ srcs,
    const float* __restrict__ dis, const float* __restrict__ b1,
    __half* __restrict__ acc) {
  const int t = threadIdx.x;
  const int g = t >> 5, lane = t & 31;
  const int n = blockIdx.x * 8 + g;
  if (n >= N_NODES) return;
  float4 sum;
  {
    uint2 raw = *(const uint2*)(hs + (size_t)n * 128 + lane * 4);  // self-loop
    float2 fa = __half22float2(*(__half2*)&raw.x);
    float2 fb = __half22float2(*(__half2*)&raw.y);
    sum = make_float4(fa.x, fa.y, fb.x, fb.y);
  }
  const int s0 = startp[n];
  const int e0 = s0 + cnt[n];
  int j = s0;
  for (; j + 4 <= e0; j += 4) {
    int i0 = srcs[j], i1 = srcs[j + 1], i2 = srcs[j + 2], i3 = srcs[j + 3];
    uint2 r0 = *(const uint2*)(hs + (size_t)i0 * 128 + lane * 4);
    uint2 r1 = *(const uint2*)(hs + (size_t)i1 * 128 + lane * 4);
    uint2 r2 = *(const uint2*)(hs + (size_t)i2 * 128 + lane * 4);
    uint2 r3 = *(const uint2*)(hs + (size_t)i3 * 128 + lane * 4);
    float2 a0 = __half22float2(*(__half2*)&r0.x), b0 = __half22float2(*(__half2*)&r0.y);
    float2 a1 = __half22float2(*(__half2*)&r1.x), b1f = __half22float2(*(__half2*)&r1.y);
    float2 a2 = __half22float2(*(__half2*)&r2.x), b2 = __half22float2(*(__half2*)&r2.y);
    float2 a3 = __half22float2(*(__half2*)&r3.x), b3 = __half22float2(*(__half2*)&r3.y);
    sum.x += (a0.x + a1.x) + (a2.x + a3.x);
    sum.y += (a0.y + a1.y) + (a2.y + a3.y);
    sum.z += (b0.x + b1f.x) + (b2.x + b3.x);
    sum.w += (b0.y + b1f.y) + (b2.y + b3.y);
  }
  for (; j < e0; ++j) {
    int src = srcs[j];
    uint2 r0 = *(const uint2*)(hs + (size_t)src * 128 + lane * 4);
    float2 a0 = __half22float2(*(__half2*)&r0.x), b0 = __half22float2(*(__half2*)&r0.y);
    sum.x += a0.x; sum.y += a0.y; sum.z += b0.x; sum.w += b0.y;
  }
  float d = dis[n];
  float4 b = *(const float4*)(b1 + lane * 4);
  union { __half2 h[2]; uint2 v; } u;
  u.h[0] = __floats2half2_rn(fmaf(d, sum.x, b.x), fmaf(d, sum.y, b.y));
  u.h[1] = __floats2half2_rn(fmaf(d, sum.z, b.z), fmaf(d, sum.w, b.w));
  *(uint2*)(acc + (size_t)n * 128 + lane * 4) = u.v;
}

// out[n] = log_softmax(relu(acc[n]) @ linW + linb)   -- 4 lanes/node
__global__ __launch_bounds__(256) void k_final(
    const __half* __restrict__ acc, const float* __restrict__ linW,
    const float* __restrict__ linb, float* __restrict__ out) {
  __shared__ float vs[64][132];
  __shared__ float wl[128 * 40];
  __shared__ float lb[40];
  const int t = threadIdx.x;
  const int n0 = blockIdx.x * 64;
#pragma unroll
  for (int i = 0; i < 5; ++i) {
    int lin = i * 256 + t;
    ((float4*)wl)[lin] = ((const float4*)linW)[lin];
  }
  if (t < 40) lb[t] = linb[t];
#pragma unroll
  for (int i = 0; i < 4; ++i) {
    int lin = i * 256 + t;          // 1024 chunks of 8 halves
    int r = lin >> 4, c8 = lin & 15;
    int n = n0 + r;
    float vals[8];
#pragma unroll
    for (int q = 0; q < 8; ++q) vals[q] = 0.f;
    if (n < N_NODES) {
      uint4 raw = *(const uint4*)(acc + (size_t)n * 128 + c8 * 8);
      const __half2* hp = (const __half2*)&raw;
#pragma unroll
      for (int q = 0; q < 4; ++q) {
        float2 f = __half22float2(hp[q]);
        vals[2 * q]     = fmaxf(f.x, 0.f);
        vals[2 * q + 1] = fmaxf(f.y, 0.f);
      }
    }
#pragma unroll
    for (int q = 0; q < 8; ++q) vs[r][c8 * 8 + q] = vals[q];
  }
  __syncthreads();
  const int nl = t >> 2, l4 = t & 3;
  const int n = n0 + nl;
  if (n >= N_NODES) return;
  float lg[10];
#pragma unroll
  for (int j = 0; j < 10; ++j) lg[j] = lb[l4 * 10 + j];
  for (int k = 0; k < 128; ++k) {
    float vk = vs[nl][k];
#pragma unroll
    for (int j = 0; j < 10; ++j) lg[j] = fmaf(vk, wl[k * 40 + l4 * 10 + j], lg[j]);
  }
  float m = lg[0];
#pragma unroll
  for (int j = 1; j < 10; ++j) m = fmaxf(m, lg[j]);
  m = fmaxf(m, __shfl_xor(m, 1));
  m = fmaxf(m, __shfl_xor(m, 2));
  float s = 0.f;
#pragma unroll
  for (int j = 0; j < 10; ++j) s += expf(lg[j] - m);
  s += __shfl_xor(s, 1);
  s += __shfl_xor(s, 2);
  float lse = m + logf(s);
#pragma unroll
  for (int j = 0; j < 10; ++j) out[(size_t)n * 40 + l4 * 10 + j] = lg[j] - lse;
}

extern "C" void kernel_launch(void* const* d_in, const int* in_sizes, int n_in,
                              void* d_out, int out_size, void* d_ws, size_t ws_size,
                              hipStream_t stream) {
  const float* x    = (const float*)d_in[0];
  const int*   ei   = (const int*)d_in[1];
  const float* W1   = (const float*)d_in[2];
  const float* b1   = (const float*)d_in[3];
  const float* linW = (const float*)d_in[4];
  const float* linb = (const float*)d_in[5];
  float* out = (float*)d_out;
  char* ws = (char*)d_ws;

  int*    flag   = (int*)(ws + OFF_FLAG);
  int*    btot   = (int*)(ws + OFF_BTOT);
  int*    ubtot  = (int*)(ws + OFF_UBTOT);
  int*    bbase  = (int*)(ws + OFF_BBASE);
  int*    cbase  = (int*)(ws + OFF_CBASE);
  float*  dis    = (float*)(ws + OFF_DIS);
  int*    cnt    = (int*)(ws + OFF_CNT);
  int*    startp = (int*)(ws + OFF_START);
  int*    srcs   = (int*)(ws + OFF_SRCS);
  __half* hs     = (__half*)(ws + OFF_HS);
  int*    ghist  = (int*)(ws + OFF_GHIST);
  int*    gchoff = (int*)(ws + OFF_GCHOFF);
  int2*   dump   = (int2*)(ws + OFF_DUMP);
  __half* acc    = (__half*)(ws + OFF_ACC);

  k_detect<<<1, 256, 0, stream>>>(ei, flag);
  k_hist<<<NB_HIST, 256, 0, stream>>>(ei, flag, ghist);
  k_bucket_scan<<<NBUCK, 256, 0, stream>>>(ghist, gchoff, btot, ubtot);
  k_scan_tot<<<1, 1024, 0, stream>>>(btot, bbase);
  k_scan_tot<<<1, 1024, 0, stream>>>(ubtot, cbase);
  k_bin<<<NB_BIN, 256, 0, stream>>>(ei, flag, bbase, gchoff, dump);
  k_csr<<<NBUCK, 256, 0, stream>>>(dump, bbase, cbase, srcs, startp, cnt, dis);
  k_gemm1<<<NBUCK, 256, 0, stream>>>(x, W1, dis, hs);
  k_agg<<<(N_NODES + 7) / 8, 256, 0, stream>>>(hs, startp, cnt, srcs, dis, b1, acc);
  k_final<<<NBUCK, 256, 0, stream>>>(acc, linW, linb, out);
}

// Round 6
// 240.179 us; speedup vs baseline: 5.7017x; 1.1238x over previous
//
#include <hip/hip_runtime.h>
#include <hip/hip_fp16.h>
#include <math.h>

#define N_NODES 100000
#define N_EDGES 1600000
#define NBUCK   1563          // ceil(100000/64) buckets of 64 dst nodes
#define NBUCK_P 1568          // padded row length for hist tables
#define NB_HIST 256           // hist blocks (slice 6250)
#define NB_BIN  64            // bin blocks (slice 25000)

// ws layout (bytes). acc aliases {ghist,gchoff,dump}: dead before k_agg writes.
#define OFF_FLAG   0x0u
#define OFF_BTOT   0x1000u     // int[NBUCK_P]   padded bucket totals
#define OFF_UBTOT  0x3000u     // int[NBUCK_P]   unpadded bucket totals
#define OFF_BBASE  0x5000u     // int[NBUCK+1]   padded scan (dump base)
#define OFF_CBASE  0x7000u     // int[NBUCK+1]   compact scan (srcs base)
#define OFF_DIS    0x9000u     // float[N_NODES]
#define OFF_CNT    0x70000u    // int[N_NODES]
#define OFF_START  0xE0000u    // int[N_NODES]
#define OFF_SRCS   0x150000u   // int[N_EDGES]
#define OFF_HS     0x780000u   // __half[N_NODES*128] (25.6 MB)
#define OFF_GHIST  0x3980000u  // int[NB_HIST*NBUCK_P]
#define OFF_GCHOFF 0x3B10000u  // int[NB_BIN*NBUCK_P]
#define OFF_DUMP   0x3B80000u  // int2[<=2.35M]
#define OFF_ACC    0x3980000u  // __half[N_NODES*128] aliases binning scratch

// ---- edge dtype detect: int64 edge_index has zero high words ----
__global__ void k_detect(const int* __restrict__ p32, int* __restrict__ flag) {
  __shared__ int nz;
  if (threadIdx.x == 0) nz = 0;
  __syncthreads();
  if (p32[2 * threadIdx.x + 1] != 0) atomicAdd(&nz, 1);
  __syncthreads();
  if (threadIdx.x == 0) *flag = (nz == 0) ? 1 : 0;  // 1 => int64 (stride 2)
}

// per-block bucket histogram of dst
__global__ __launch_bounds__(256) void k_hist(const int* __restrict__ p32,
                                              const int* __restrict__ flag,
                                              int* __restrict__ G_hist) {
  __shared__ int hist[NBUCK];
  const int t = threadIdx.x;
  for (int i = t; i < NBUCK; i += 256) hist[i] = 0;
  __syncthreads();
  const int base = blockIdx.x * 6250;
  const int s = *flag;
  for (int i = 0; i < 25; ++i) {
    int e = base + i * 256 + t;
    if (e < base + 6250) {
      int c = p32[((size_t)(N_EDGES + e)) << s];
      atomicAdd(&hist[c >> 6], 1);
    }
  }
  __syncthreads();
  for (int i = t; i < NBUCK; i += 256) G_hist[blockIdx.x * NBUCK_P + i] = hist[i];
}

// per bucket: 64 bin-chunk sizes (sum hist groups of 4), pad to x8, scan.
__global__ __launch_bounds__(256) void k_bucket_scan(const int* __restrict__ G_hist,
                                                     int* __restrict__ G_choff,
                                                     int* __restrict__ btot,
                                                     int* __restrict__ ubtot) {
  __shared__ int sm[256];
  const int t = threadIdx.x;
  const int b = blockIdx.x;
  sm[t] = G_hist[t * NBUCK_P + b];
  __syncthreads();
  if (t < 64) {
    int ssum = sm[4 * t] + sm[4 * t + 1] + sm[4 * t + 2] + sm[4 * t + 3];
    int p = (ssum + 7) & ~7;
    int v = p;
    int u = ssum;
    for (int d = 1; d < 64; d <<= 1) {
      int vv = __shfl_up(v, d);
      int uu = __shfl_up(u, d);
      if ((t & 63) >= d) { v += vv; u += uu; }
    }
    G_choff[t * NBUCK_P + b] = v - p;  // exclusive padded offset within bucket
    if (t == 63) { btot[b] = v; ubtot[b] = u; }
  }
}

// scan 1563 totals -> base[0..NBUCK] (exclusive); generic, 1 block
__global__ __launch_bounds__(1024) void k_scan_tot(const int* __restrict__ tot,
                                                   int* __restrict__ base) {
  __shared__ int sm[1024];
  const int t = threadIdx.x;
  int a = (2 * t < NBUCK) ? tot[2 * t] : 0;
  int bb = (2 * t + 1 < NBUCK) ? tot[2 * t + 1] : 0;
  int pair = a + bb;
  sm[t] = pair;
  __syncthreads();
  for (int off = 1; off < 1024; off <<= 1) {
    int x = (t >= off) ? sm[t - off] : 0;
    __syncthreads();
    sm[t] += x;
    __syncthreads();
  }
  int S = sm[t];
  if (2 * t <= NBUCK) base[2 * t] = S - pair;
  if (2 * t + 1 <= NBUCK) base[2 * t + 1] = S - bb;
}

// place (src,dst) records into block-private padded chunks; sentinel tails
__global__ __launch_bounds__(256) void k_bin(const int* __restrict__ p32,
                                             const int* __restrict__ flag,
                                             const int* __restrict__ bbase,
                                             const int* __restrict__ G_choff,
                                             int2* __restrict__ dump) {
  __shared__ int gb[NBUCK];
  __shared__ int cur[NBUCK];
  const int t = threadIdx.x;
  const int blk = blockIdx.x;
  for (int i = t; i < NBUCK; i += 256) {
    gb[i] = bbase[i] + G_choff[blk * NBUCK_P + i];
    cur[i] = 0;
  }
  __syncthreads();
  const int base = blk * 25000;
  const int s = *flag;
  for (int i = 0; i < 98; ++i) {
    int e = base + i * 256 + t;
    if (e < base + 25000) {
      int r = p32[((size_t)e) << s];
      int c = p32[((size_t)(N_EDGES + e)) << s];
      int bk = c >> 6;
      int p = atomicAdd(&cur[bk], 1);
      dump[gb[bk] + p] = make_int2(r, c);
    }
  }
  __syncthreads();
  for (int i = t; i < NBUCK; i += 256) {
    int c0 = cur[i], pe = (c0 + 7) & ~7;
    for (int j = c0; j < pe; ++j) dump[gb[i] + j] = make_int2(0, -1);
  }
}

// per bucket: dump chunk -> per-node CSR at COMPACT offsets + deg/dis
__global__ __launch_bounds__(256) void k_csr(const int2* __restrict__ dump,
                                             const int* __restrict__ bbase,
                                             const int* __restrict__ cbase,
                                             int* __restrict__ srcs,
                                             int* __restrict__ startp,
                                             int* __restrict__ cnt,
                                             float* __restrict__ dis) {
  __shared__ int cnt_s[64];
  __shared__ int off_s[64];
  __shared__ int cur_s[64];
  __shared__ int stage[3072];
  const int t = threadIdx.x;
  const int b = blockIdx.x;
  if (t < 64) cnt_s[t] = 0;
  __syncthreads();
  const int rb = bbase[b];
  const int m = bbase[b + 1] - rb;
  const int cb = cbase[b];
  for (int j = t; j < m; j += 256) {
    int2 rec = dump[rb + j];
    if (rec.y >= 0) atomicAdd(&cnt_s[rec.y & 63], 1);
  }
  __syncthreads();
  if (t < 64) {
    int v = cnt_s[t];
    int sv = v;
    for (int d = 1; d < 64; d <<= 1) {
      int u = __shfl_up(sv, d);
      if (t >= d) sv += u;
    }
    off_s[t] = sv - v;
    cur_s[t] = sv - v;
  }
  __syncthreads();
  for (int j = t; j < m; j += 256) {
    int2 rec = dump[rb + j];
    if (rec.y >= 0) {
      int p = atomicAdd(&cur_s[rec.y & 63], 1);
      stage[p] = rec.x;
    }
  }
  __syncthreads();
  const int total = off_s[63] + cnt_s[63];
  for (int j = t; j < total; j += 256) srcs[cb + j] = stage[j];
  if (t < 64) {
    int n = (b << 6) + t;
    if (n < N_NODES) {
      cnt[n] = cnt_s[t];
      startp[n] = cb + off_s[t];
      dis[n] = rsqrtf((float)cnt_s[t] + 1.0f);
    }
  }
}

// hs[n] = fp16( dis[n] * (x @ W1)[n] )
// 64 rows/block, thread = 4 rows x 8 cols; W staged in 32-row K-chunks.
// wsm col c stored at c + 4*(c>>5)  (row stride 140): read pattern <=2-way bank.
__global__ __launch_bounds__(256, 3) void k_gemm1(
    const float* __restrict__ x, const float* __restrict__ W,
    const float* __restrict__ dis, __half* __restrict__ hs) {
  __shared__ float xs[64][132];
  __shared__ float wsm[32][140];
  const int t = threadIdx.x;
  const int row0 = blockIdx.x * 64;
#pragma unroll
  for (int i = 0; i < 8; ++i) {
    int lin = i * 256 + t;
    int r = lin >> 5, c4 = lin & 31;
    int gr = row0 + r;
    float4 v = make_float4(0.f, 0.f, 0.f, 0.f);
    if (gr < N_NODES) v = *(const float4*)(x + (size_t)gr * 128 + c4 * 4);
    xs[r][c4 * 4 + 0] = v.x; xs[r][c4 * 4 + 1] = v.y;
    xs[r][c4 * 4 + 2] = v.z; xs[r][c4 * 4 + 3] = v.w;
  }
  const int ty = t >> 4, tx = t & 15;
  const int wcol = tx * 8 + ((tx >> 2) << 2);  // swizzled base col for this thread
  float acc[4][8];
#pragma unroll
  for (int i = 0; i < 4; ++i)
#pragma unroll
    for (int j = 0; j < 8; ++j) acc[i][j] = 0.f;

  for (int kc = 0; kc < 4; ++kc) {
    __syncthreads();  // (first iter: also covers xs staging)
    // stage W rows kc*32 .. kc*32+31 (1024 float4s)
#pragma unroll
    for (int i = 0; i < 4; ++i) {
      int lin = i * 256 + t;
      int r = lin >> 5, c = (lin & 31) * 4;
      float4 v = *(const float4*)(W + (size_t)(kc * 32 + r) * 128 + c);
      *(float4*)&wsm[r][c + ((c >> 5) << 2)] = v;
    }
    __syncthreads();
#pragma unroll 4
    for (int kk = 0; kk < 32; ++kk) {
      int k = kc * 32 + kk;
      float xv[4];
#pragma unroll
      for (int i = 0; i < 4; ++i) xv[i] = xs[ty * 4 + i][k];
      float4 wa = *(const float4*)&wsm[kk][wcol];
      float4 wb = *(const float4*)&wsm[kk][wcol + 4];
      float wv[8] = {wa.x, wa.y, wa.z, wa.w, wb.x, wb.y, wb.z, wb.w};
#pragma unroll
      for (int i = 0; i < 4; ++i)
#pragma unroll
        for (int j = 0; j < 8; ++j) acc[i][j] = fmaf(xv[i], wv[j], acc[i][j]);
    }
  }
#pragma unroll
  for (int i = 0; i < 4; ++i) {
    int r = row0 + ty * 4 + i;
    if (r >= N_NODES) continue;
    float d = dis[r];
    union { __half2 h[4]; int4 v; } u;
    u.h[0] = __floats2half2_rn(acc[i][0] * d, acc[i][1] * d);
    u.h[1] = __floats2half2_rn(acc[i][2] * d, acc[i][3] * d);
    u.h[2] = __floats2half2_rn(acc[i][4] * d, acc[i][5] * d);
    u.h[3] = __floats2half2_rn(acc[i][6] * d, acc[i][7] * d);
    *(int4*)(hs + (size_t)r * 128 + tx * 8) = u.v;  // 16B aligned
  }
}

// acc[n] = fp16( dis[n]*(hs[n] + sum_in hs[src]) + b1 )  -- 32 lanes/node
__global__ __launch_bounds__(256) void k_agg(
    const __half* __restrict__ hs, const int* __restrict__ startp,
    const int* __restrict__ cnt, const int* __restrict__ srcs,
    const float* __restrict__ dis, const float* __restrict__ b1,
    __half* __restrict__ acc) {
  const int t = threadIdx.x;
  const int g = t >> 5, lane = t & 31;
  const int n = blockIdx.x * 8 + g;
  if (n >= N_NODES) return;
  float4 sum;
  {
    uint2 raw = *(const uint2*)(hs + (size_t)n * 128 + lane * 4);  // self-loop
    float2 fa = __half22float2(*(__half2*)&raw.x);
    float2 fb = __half22float2(*(__half2*)&raw.y);
    sum = make_float4(fa.x, fa.y, fb.x, fb.y);
  }
  const int s0 = startp[n];
  const int e0 = s0 + cnt[n];
  int j = s0;
  for (; j + 4 <= e0; j += 4) {
    int i0 = srcs[j], i1 = srcs[j + 1], i2 = srcs[j + 2], i3 = srcs[j + 3];
    uint2 r0 = *(const uint2*)(hs + (size_t)i0 * 128 + lane * 4);
    uint2 r1 = *(const uint2*)(hs + (size_t)i1 * 128 + lane * 4);
    uint2 r2 = *(const uint2*)(hs + (size_t)i2 * 128 + lane * 4);
    uint2 r3 = *(const uint2*)(hs + (size_t)i3 * 128 + lane * 4);
    float2 a0 = __half22float2(*(__half2*)&r0.x), b0 = __half22float2(*(__half2*)&r0.y);
    float2 a1 = __half22float2(*(__half2*)&r1.x), b1f = __half22float2(*(__half2*)&r1.y);
    float2 a2 = __half22float2(*(__half2*)&r2.x), b2 = __half22float2(*(__half2*)&r2.y);
    float2 a3 = __half22float2(*(__half2*)&r3.x), b3 = __half22float2(*(__half2*)&r3.y);
    sum.x += (a0.x + a1.x) + (a2.x + a3.x);
    sum.y += (a0.y + a1.y) + (a2.y + a3.y);
    sum.z += (b0.x + b1f.x) + (b2.x + b3.x);
    sum.w += (b0.y + b1f.y) + (b2.y + b3.y);
  }
  for (; j < e0; ++j) {
    int src = srcs[j];
    uint2 r0 = *(const uint2*)(hs + (size_t)src * 128 + lane * 4);
    float2 a0 = __half22float2(*(__half2*)&r0.x), b0 = __half22float2(*(__half2*)&r0.y);
    sum.x += a0.x; sum.y += a0.y; sum.z += b0.x; sum.w += b0.y;
  }
  float d = dis[n];
  float4 b = *(const float4*)(b1 + lane * 4);
  union { __half2 h[2]; uint2 v; } u;
  u.h[0] = __floats2half2_rn(fmaf(d, sum.x, b.x), fmaf(d, sum.y, b.y));
  u.h[1] = __floats2half2_rn(fmaf(d, sum.z, b.z), fmaf(d, sum.w, b.w));
  *(uint2*)(acc + (size_t)n * 128 + lane * 4) = u.v;
}

// out[n] = log_softmax(relu(acc[n]) @ linW + linb)   -- 4 lanes/node
__global__ __launch_bounds__(256) void k_final(
    const __half* __restrict__ acc, const float* __restrict__ linW,
    const float* __restrict__ linb, float* __restrict__ out) {
  __shared__ float vs[64][132];
  __shared__ float wl[128 * 40];
  __shared__ float lb[40];
  const int t = threadIdx.x;
  const int n0 = blockIdx.x * 64;
#pragma unroll
  for (int i = 0; i < 5; ++i) {
    int lin = i * 256 + t;
    ((float4*)wl)[lin] = ((const float4*)linW)[lin];
  }
  if (t < 40) lb[t] = linb[t];
#pragma unroll
  for (int i = 0; i < 4; ++i) {
    int lin = i * 256 + t;          // 1024 chunks of 8 halves
    int r = lin >> 4, c8 = lin & 15;
    int n = n0 + r;
    float vals[8];
#pragma unroll
    for (int q = 0; q < 8; ++q) vals[q] = 0.f;
    if (n < N_NODES) {
      uint4 raw = *(const uint4*)(acc + (size_t)n * 128 + c8 * 8);
      const __half2* hp = (const __half2*)&raw;
#pragma unroll
      for (int q = 0; q < 4; ++q) {
        float2 f = __half22float2(hp[q]);
        vals[2 * q]     = fmaxf(f.x, 0.f);
        vals[2 * q + 1] = fmaxf(f.y, 0.f);
      }
    }
#pragma unroll
    for (int q = 0; q < 8; ++q) vs[r][c8 * 8 + q] = vals[q];
  }
  __syncthreads();
  const int nl = t >> 2, l4 = t & 3;
  const int n = n0 + nl;
  if (n >= N_NODES) return;
  float lg[10];
#pragma unroll
  for (int j = 0; j < 10; ++j) lg[j] = lb[l4 * 10 + j];
  for (int k = 0; k < 128; ++k) {
    float vk = vs[nl][k];
#pragma unroll
    for (int j = 0; j < 10; ++j) lg[j] = fmaf(vk, wl[k * 40 + l4 * 10 + j], lg[j]);
  }
  float m = lg[0];
#pragma unroll
  for (int j = 1; j < 10; ++j) m = fmaxf(m, lg[j]);
  m = fmaxf(m, __shfl_xor(m, 1));
  m = fmaxf(m, __shfl_xor(m, 2));
  float s = 0.f;
#pragma unroll
  for (int j = 0; j < 10; ++j) s += expf(lg[j] - m);
  s += __shfl_xor(s, 1);
  s += __shfl_xor(s, 2);
  float lse = m + logf(s);
#pragma unroll
  for (int j = 0; j < 10; ++j) out[(size_t)n * 40 + l4 * 10 + j] = lg[j] - lse;
}

extern "C" void kernel_launch(void* const* d_in, const int* in_sizes, int n_in,
                              void* d_out, int out_size, void* d_ws, size_t ws_size,
                              hipStream_t stream) {
  const float* x    = (const float*)d_in[0];
  const int*   ei   = (const int*)d_in[1];
  const float* W1   = (const float*)d_in[2];
  const float* b1   = (const float*)d_in[3];
  const float* linW = (const float*)d_in[4];
  const float* linb = (const float*)d_in[5];
  float* out = (float*)d_out;
  char* ws = (char*)d_ws;

  int*    flag   = (int*)(ws + OFF_FLAG);
  int*    btot   = (int*)(ws + OFF_BTOT);
  int*    ubtot  = (int*)(ws + OFF_UBTOT);
  int*    bbase  = (int*)(ws + OFF_BBASE);
  int*    cbase  = (int*)(ws + OFF_CBASE);
  float*  dis    = (float*)(ws + OFF_DIS);
  int*    cnt    = (int*)(ws + OFF_CNT);
  int*    startp = (int*)(ws + OFF_START);
  int*    srcs   = (int*)(ws + OFF_SRCS);
  __half* hs     = (__half*)(ws + OFF_HS);
  int*    ghist  = (int*)(ws + OFF_GHIST);
  int*    gchoff = (int*)(ws + OFF_GCHOFF);
  int2*   dump   = (int2*)(ws + OFF_DUMP);
  __half* acc    = (__half*)(ws + OFF_ACC);

  k_detect<<<1, 256, 0, stream>>>(ei, flag);
  k_hist<<<NB_HIST, 256, 0, stream>>>(ei, flag, ghist);
  k_bucket_scan<<<NBUCK, 256, 0, stream>>>(ghist, gchoff, btot, ubtot);
  k_scan_tot<<<1, 1024, 0, stream>>>(btot, bbase);
  k_scan_tot<<<1, 1024, 0, stream>>>(ubtot, cbase);
  k_bin<<<NB_BIN, 256, 0, stream>>>(ei, flag, bbase, gchoff, dump);
  k_csr<<<NBUCK, 256, 0, stream>>>(dump, bbase, cbase, srcs, startp, cnt, dis);
  k_gemm1<<<NBUCK, 256, 0, stream>>>(x, W1, dis, hs);
  k_agg<<<(N_NODES + 7) / 8, 256, 0, stream>>>(hs, startp, cnt, srcs, dis, b1, acc);
  k_final<<<NBUCK, 256, 0, stream>>>(acc, linW, linb, out);
}

// Round 7
// 207.914 us; speedup vs baseline: 6.5865x; 1.1552x over previous
//
#include <hip/hip_runtime.h>
#include <hip/hip_fp16.h>
#include <math.h>

#define N_NODES 100000
#define N_EDGES 1600000
#define NBUCK   1563          // ceil(100000/64) buckets of 64 dst nodes
#define NBUCK_P 1568          // padded row length for hist tables
#define NB_HIST 256           // hist blocks (slice 6250)
#define NB_BIN  64            // bin blocks (slice 25000)

// ws layout (bytes). acc aliases {ghist,gchoff,dump}: dead before k_agg writes.
#define OFF_FLAG   0x0u
#define OFF_BTOT   0x1000u     // int[NBUCK_P]   padded bucket totals
#define OFF_UBTOT  0x3000u     // int[NBUCK_P]   unpadded bucket totals
#define OFF_BBASE  0x5000u     // int[NBUCK+1]   padded scan (dump base)
#define OFF_CBASE  0x7000u     // int[NBUCK+1]   compact scan (srcs base)
#define OFF_DIS    0x9000u     // float[N_NODES]
#define OFF_CNT    0x70000u    // int[N_NODES]
#define OFF_START  0xE0000u    // int[N_NODES]
#define OFF_SRCS   0x150000u   // int[N_EDGES]
#define OFF_HS     0x780000u   // __half[N_NODES*128] (25.6 MB, ends 0x1FEA000)
#define OFF_WT     0x2100000u  // __half[128*128] fp16 W1^T (32 KB)
#define OFF_GHIST  0x3980000u  // int[NB_HIST*NBUCK_P]
#define OFF_GCHOFF 0x3B10000u  // int[NB_BIN*NBUCK_P]
#define OFF_DUMP   0x3B80000u  // int2[<=2.35M]
#define OFF_ACC    0x3980000u  // __half[N_NODES*128] aliases binning scratch

typedef _Float16 half8_t __attribute__((ext_vector_type(8)));
typedef float f32x4_t __attribute__((ext_vector_type(4)));

// ---- edge dtype detect: int64 edge_index has zero high words ----
__global__ void k_detect(const int* __restrict__ p32, int* __restrict__ flag) {
  __shared__ int nz;
  if (threadIdx.x == 0) nz = 0;
  __syncthreads();
  if (p32[2 * threadIdx.x + 1] != 0) atomicAdd(&nz, 1);
  __syncthreads();
  if (threadIdx.x == 0) *flag = (nz == 0) ? 1 : 0;  // 1 => int64 (stride 2)
}

// W1 (f32 [128k][128n]) -> Wt (fp16 [128n][128k]); block b owns k rows [8b,8b+8)
__global__ __launch_bounds__(256) void k_wt(const float* __restrict__ W,
                                            __half* __restrict__ Wt) {
  __shared__ float buf[1024];
  const int t = threadIdx.x;
  const int b = blockIdx.x;
  float4 v = ((const float4*)(W + (size_t)b * 1024))[t];
  *(float4*)&buf[t * 4] = v;
  __syncthreads();
  if (t < 128) {
    union { __half h[8]; int4 v; } u;
#pragma unroll
    for (int k = 0; k < 8; ++k) u.h[k] = __float2half(buf[k * 128 + t]);
    *(int4*)&Wt[(size_t)t * 128 + b * 8] = u.v;
  }
}

// per-block bucket histogram of dst
__global__ __launch_bounds__(256) void k_hist(const int* __restrict__ p32,
                                              const int* __restrict__ flag,
                                              int* __restrict__ G_hist) {
  __shared__ int hist[NBUCK];
  const int t = threadIdx.x;
  for (int i = t; i < NBUCK; i += 256) hist[i] = 0;
  __syncthreads();
  const int base = blockIdx.x * 6250;
  const int s = *flag;
  for (int i = 0; i < 25; ++i) {
    int e = base + i * 256 + t;
    if (e < base + 6250) {
      int c = p32[((size_t)(N_EDGES + e)) << s];
      atomicAdd(&hist[c >> 6], 1);
    }
  }
  __syncthreads();
  for (int i = t; i < NBUCK; i += 256) G_hist[blockIdx.x * NBUCK_P + i] = hist[i];
}

// per bucket: 64 bin-chunk sizes (sum hist groups of 4), pad to x8, scan.
__global__ __launch_bounds__(256) void k_bucket_scan(const int* __restrict__ G_hist,
                                                     int* __restrict__ G_choff,
                                                     int* __restrict__ btot,
                                                     int* __restrict__ ubtot) {
  __shared__ int sm[256];
  const int t = threadIdx.x;
  const int b = blockIdx.x;
  sm[t] = G_hist[t * NBUCK_P + b];
  __syncthreads();
  if (t < 64) {
    int ssum = sm[4 * t] + sm[4 * t + 1] + sm[4 * t + 2] + sm[4 * t + 3];
    int p = (ssum + 7) & ~7;
    int v = p;
    int u = ssum;
    for (int d = 1; d < 64; d <<= 1) {
      int vv = __shfl_up(v, d);
      int uu = __shfl_up(u, d);
      if ((t & 63) >= d) { v += vv; u += uu; }
    }
    G_choff[t * NBUCK_P + b] = v - p;  // exclusive padded offset within bucket
    if (t == 63) { btot[b] = v; ubtot[b] = u; }
  }
}

// scan 1563 totals -> base[0..NBUCK] (exclusive); generic, 1 block
__global__ __launch_bounds__(1024) void k_scan_tot(const int* __restrict__ tot,
                                                   int* __restrict__ base) {
  __shared__ int sm[1024];
  const int t = threadIdx.x;
  int a = (2 * t < NBUCK) ? tot[2 * t] : 0;
  int bb = (2 * t + 1 < NBUCK) ? tot[2 * t + 1] : 0;
  int pair = a + bb;
  sm[t] = pair;
  __syncthreads();
  for (int off = 1; off < 1024; off <<= 1) {
    int x = (t >= off) ? sm[t - off] : 0;
    __syncthreads();
    sm[t] += x;
    __syncthreads();
  }
  int S = sm[t];
  if (2 * t <= NBUCK) base[2 * t] = S - pair;
  if (2 * t + 1 <= NBUCK) base[2 * t + 1] = S - bb;
}

// place (src,dst) records into block-private padded chunks; sentinel tails
__global__ __launch_bounds__(512) void k_bin(const int* __restrict__ p32,
                                             const int* __restrict__ flag,
                                             const int* __restrict__ bbase,
                                             const int* __restrict__ G_choff,
                                             int2* __restrict__ dump) {
  __shared__ int gb[NBUCK];
  __shared__ int cur[NBUCK];
  const int t = threadIdx.x;
  const int blk = blockIdx.x;
  for (int i = t; i < NBUCK; i += 512) {
    gb[i] = bbase[i] + G_choff[blk * NBUCK_P + i];
    cur[i] = 0;
  }
  __syncthreads();
  const int base = blk * 25000;
  const int s = *flag;
  for (int i = 0; i < 49; ++i) {
    int e = base + i * 512 + t;
    if (e < base + 25000) {
      int r = p32[((size_t)e) << s];
      int c = p32[((size_t)(N_EDGES + e)) << s];
      int bk = c >> 6;
      int p = atomicAdd(&cur[bk], 1);
      dump[gb[bk] + p] = make_int2(r, c);
    }
  }
  __syncthreads();
  for (int i = t; i < NBUCK; i += 512) {
    int c0 = cur[i], pe = (c0 + 7) & ~7;
    for (int j = c0; j < pe; ++j) dump[gb[i] + j] = make_int2(0, -1);
  }
}

// per bucket: dump chunk -> per-node CSR at COMPACT offsets + deg/dis
__global__ __launch_bounds__(512) void k_csr(const int2* __restrict__ dump,
                                             const int* __restrict__ bbase,
                                             const int* __restrict__ cbase,
                                             int* __restrict__ srcs,
                                             int* __restrict__ startp,
                                             int* __restrict__ cnt,
                                             float* __restrict__ dis) {
  __shared__ int cnt_s[64];
  __shared__ int off_s[64];
  __shared__ int cur_s[64];
  __shared__ int stage[3072];
  const int t = threadIdx.x;
  const int b = blockIdx.x;
  if (t < 64) cnt_s[t] = 0;
  __syncthreads();
  const int rb = bbase[b];
  const int m = bbase[b + 1] - rb;
  const int cb = cbase[b];
  for (int j = t; j < m; j += 512) {
    int2 rec = dump[rb + j];
    if (rec.y >= 0) atomicAdd(&cnt_s[rec.y & 63], 1);
  }
  __syncthreads();
  if (t < 64) {
    int v = cnt_s[t];
    int sv = v;
    for (int d = 1; d < 64; d <<= 1) {
      int u = __shfl_up(sv, d);
      if (t >= d) sv += u;
    }
    off_s[t] = sv - v;
    cur_s[t] = sv - v;
  }
  __syncthreads();
  for (int j = t; j < m; j += 512) {
    int2 rec = dump[rb + j];
    if (rec.y >= 0) {
      int p = atomicAdd(&cur_s[rec.y & 63], 1);
      stage[p] = rec.x;
    }
  }
  __syncthreads();
  const int total = off_s[63] + cnt_s[63];
  for (int j = t; j < total; j += 512) srcs[cb + j] = stage[j];
  if (t < 64) {
    int n = (b << 6) + t;
    if (n < N_NODES) {
      cnt[n] = cnt_s[t];
      startp[n] = cb + off_s[t];
      dis[n] = rsqrtf((float)cnt_s[t] + 1.0f);
    }
  }
}

// hs[n] = fp16( dis[n] * (x @ W1)[n] )  via MFMA f16.
// Block: 64 rows; 4 waves, wave w owns rows w*16..w*16+15 (all 128 cols).
// Fragments (mfma_f32_16x16x32_f16): A lane l: row=l&15, k=8*(l>>4)+j (contig);
// B lane l: col=l&15, same k. C/D: col=l&15, row=4*(l>>4)+reg.
__global__ __launch_bounds__(256, 3) void k_gemm1(
    const float* __restrict__ x, const __half* __restrict__ Wt,
    const float* __restrict__ dis, __half* __restrict__ hs) {
  __shared__ _Float16 xt[64 * 136];   // row stride 136 halves (272 B, 16B-mult)
  __shared__ _Float16 wt[128 * 136];  // wt[n][k] (B operand, transposed W)
  const int t = threadIdx.x;
  const int row0 = blockIdx.x * 64;
  // stage x tile -> fp16
#pragma unroll
  for (int i = 0; i < 8; ++i) {
    int lin = i * 256 + t;
    int r = lin >> 5, c4 = lin & 31;
    int gr = row0 + r;
    float4 v = make_float4(0.f, 0.f, 0.f, 0.f);
    if (gr < N_NODES) v = *(const float4*)(x + (size_t)gr * 128 + c4 * 4);
    union { __half2 h2[2]; int2 iv; } u;
    u.h2[0] = __floats2half2_rn(v.x, v.y);
    u.h2[1] = __floats2half2_rn(v.z, v.w);
    *(int2*)&xt[r * 136 + c4 * 4] = u.iv;
  }
  // stage Wt (already fp16) -> LDS
#pragma unroll
  for (int i = 0; i < 8; ++i) {
    int lin = i * 256 + t;
    int n = lin >> 4, kb = lin & 15;
    int4 v = *(const int4*)(Wt + (size_t)n * 128 + kb * 8);
    *(int4*)&wt[n * 136 + kb * 8] = v;
  }
  __syncthreads();

  const int w = t >> 6, l = t & 63;
  const int r = l & 15, g = l >> 4;
  const _Float16* ap = &xt[(w * 16 + r) * 136 + g * 8];
  half8_t af[4];
#pragma unroll
  for (int ks = 0; ks < 4; ++ks) af[ks] = *(const half8_t*)&ap[ks * 32];

  // dis for this lane's 4 output rows
  const int rbase = row0 + w * 16 + g * 4;
  float dv[4];
#pragma unroll
  for (int j = 0; j < 4; ++j) {
    int rr = rbase + j;
    dv[j] = (rr < N_NODES) ? dis[rr] : 0.f;
  }

#pragma unroll
  for (int ct = 0; ct < 8; ++ct) {
    f32x4_t acc = {0.f, 0.f, 0.f, 0.f};
    const _Float16* bp = &wt[(ct * 16 + r) * 136 + g * 8];
#pragma unroll
    for (int ks = 0; ks < 4; ++ks) {
      half8_t bf = *(const half8_t*)&bp[ks * 32];
      acc = __builtin_amdgcn_mfma_f32_16x16x32_f16(af[ks], bf, acc, 0, 0, 0);
    }
#pragma unroll
    for (int j = 0; j < 4; ++j) {
      int rr = rbase + j;
      if (rr < N_NODES)
        hs[(size_t)rr * 128 + ct * 16 + r] = __float2half(acc[j] * dv[j]);
    }
  }
}

// acc[n] = fp16( dis[n]*(hs[n] + sum_in hs[src]) + b1 )  -- 32 lanes/node
__global__ __launch_bounds__(256) void k_agg(
    const __half* __restrict__ hs, const int* __restrict__ startp,
    const int* __restrict__ cnt, const int* __restrict__ srcs,
    const float* __restrict__ dis, const float* __restrict__ b1,
    __half* __restrict__ acc) {
  const int t = threadIdx.x;
  const int g = t >> 5, lane = t & 31;
  const int n = blockIdx.x * 8 + g;
  if (n >= N_NODES) return;
  float4 sum;
  {
    uint2 raw = *(const uint2*)(hs + (size_t)n * 128 + lane * 4);  // self-loop
    float2 fa = __half22float2(*(__half2*)&raw.x);
    float2 fb = __half22float2(*(__half2*)&raw.y);
    sum = make_float4(fa.x, fa.y, fb.x, fb.y);
  }
  const int s0 = startp[n];
  const int e0 = s0 + cnt[n];
  int j = s0;
  for (; j + 4 <= e0; j += 4) {
    int i0 = srcs[j], i1 = srcs[j + 1], i2 = srcs[j + 2], i3 = srcs[j + 3];
    uint2 r0 = *(const uint2*)(hs + (size_t)i0 * 128 + lane * 4);
    uint2 r1 = *(const uint2*)(hs + (size_t)i1 * 128 + lane * 4);
    uint2 r2 = *(const uint2*)(hs + (size_t)i2 * 128 + lane * 4);
    uint2 r3 = *(const uint2*)(hs + (size_t)i3 * 128 + lane * 4);
    float2 a0 = __half22float2(*(__half2*)&r0.x), b0 = __half22float2(*(__half2*)&r0.y);
    float2 a1 = __half22float2(*(__half2*)&r1.x), b1f = __half22float2(*(__half2*)&r1.y);
    float2 a2 = __half22float2(*(__half2*)&r2.x), b2 = __half22float2(*(__half2*)&r2.y);
    float2 a3 = __half22float2(*(__half2*)&r3.x), b3 = __half22float2(*(__half2*)&r3.y);
    sum.x += (a0.x + a1.x) + (a2.x + a3.x);
    sum.y += (a0.y + a1.y) + (a2.y + a3.y);
    sum.z += (b0.x + b1f.x) + (b2.x + b3.x);
    sum.w += (b0.y + b1f.y) + (b2.y + b3.y);
  }
  for (; j < e0; ++j) {
    int src = srcs[j];
    uint2 r0 = *(const uint2*)(hs + (size_t)src * 128 + lane * 4);
    float2 a0 = __half22float2(*(__half2*)&r0.x), b0 = __half22float2(*(__half2*)&r0.y);
    sum.x += a0.x; sum.y += a0.y; sum.z += b0.x; sum.w += b0.y;
  }
  float d = dis[n];
  float4 b = *(const float4*)(b1 + lane * 4);
  union { __half2 h[2]; uint2 v; } u;
  u.h[0] = __floats2half2_rn(fmaf(d, sum.x, b.x), fmaf(d, sum.y, b.y));
  u.h[1] = __floats2half2_rn(fmaf(d, sum.z, b.z), fmaf(d, sum.w, b.w));
  *(uint2*)(acc + (size_t)n * 128 + lane * 4) = u.v;
}

// out[n] = log_softmax(relu(acc[n]) @ linW + linb)   -- 4 lanes/node
__global__ __launch_bounds__(256) void k_final(
    const __half* __restrict__ acc, const float* __restrict__ linW,
    const float* __restrict__ linb, float* __restrict__ out) {
  __shared__ float vs[64][132];
  __shared__ float wl[128 * 40];
  __shared__ float lb[40];
  const int t = threadIdx.x;
  const int n0 = blockIdx.x * 64;
#pragma unroll
  for (int i = 0; i < 5; ++i) {
    int lin = i * 256 + t;
    ((float4*)wl)[lin] = ((const float4*)linW)[lin];
  }
  if (t < 40) lb[t] = linb[t];
#pragma unroll
  for (int i = 0; i < 4; ++i) {
    int lin = i * 256 + t;          // 1024 chunks of 8 halves
    int r = lin >> 4, c8 = lin & 15;
    int n = n0 + r;
    float vals[8];
#pragma unroll
    for (int q = 0; q < 8; ++q) vals[q] = 0.f;
    if (n < N_NODES) {
      uint4 raw = *(const uint4*)(acc + (size_t)n * 128 + c8 * 8);
      const __half2* hp = (const __half2*)&raw;
#pragma unroll
      for (int q = 0; q < 4; ++q) {
        float2 f = __half22float2(hp[q]);
        vals[2 * q]     = fmaxf(f.x, 0.f);
        vals[2 * q + 1] = fmaxf(f.y, 0.f);
      }
    }
#pragma unroll
    for (int q = 0; q < 8; ++q) vs[r][c8 * 8 + q] = vals[q];
  }
  __syncthreads();
  const int nl = t >> 2, l4 = t & 3;
  const int n = n0 + nl;
  if (n >= N_NODES) return;
  float lg[10];
#pragma unroll
  for (int j = 0; j < 10; ++j) lg[j] = lb[l4 * 10 + j];
  for (int k = 0; k < 128; ++k) {
    float vk = vs[nl][k];
#pragma unroll
    for (int j = 0; j < 10; ++j) lg[j] = fmaf(vk, wl[k * 40 + l4 * 10 + j], lg[j]);
  }
  float m = lg[0];
#pragma unroll
  for (int j = 1; j < 10; ++j) m = fmaxf(m, lg[j]);
  m = fmaxf(m, __shfl_xor(m, 1));
  m = fmaxf(m, __shfl_xor(m, 2));
  float s = 0.f;
#pragma unroll
  for (int j = 0; j < 10; ++j) s += expf(lg[j] - m);
  s += __shfl_xor(s, 1);
  s += __shfl_xor(s, 2);
  float lse = m + logf(s);
#pragma unroll
  for (int j = 0; j < 10; ++j) out[(size_t)n * 40 + l4 * 10 + j] = lg[j] - lse;
}

extern "C" void kernel_launch(void* const* d_in, const int* in_sizes, int n_in,
                              void* d_out, int out_size, void* d_ws, size_t ws_size,
                              hipStream_t stream) {
  const float* x    = (const float*)d_in[0];
  const int*   ei   = (const int*)d_in[1];
  const float* W1   = (const float*)d_in[2];
  const float* b1   = (const float*)d_in[3];
  const float* linW = (const float*)d_in[4];
  const float* linb = (const float*)d_in[5];
  float* out = (float*)d_out;
  char* ws = (char*)d_ws;

  int*    flag   = (int*)(ws + OFF_FLAG);
  int*    btot   = (int*)(ws + OFF_BTOT);
  int*    ubtot  = (int*)(ws + OFF_UBTOT);
  int*    bbase  = (int*)(ws + OFF_BBASE);
  int*    cbase  = (int*)(ws + OFF_CBASE);
  float*  dis    = (float*)(ws + OFF_DIS);
  int*    cnt    = (int*)(ws + OFF_CNT);
  int*    startp = (int*)(ws + OFF_START);
  int*    srcs   = (int*)(ws + OFF_SRCS);
  __half* hs     = (__half*)(ws + OFF_HS);
  __half* Wt     = (__half*)(ws + OFF_WT);
  int*    ghist  = (int*)(ws + OFF_GHIST);
  int*    gchoff = (int*)(ws + OFF_GCHOFF);
  int2*   dump   = (int2*)(ws + OFF_DUMP);
  __half* acc    = (__half*)(ws + OFF_ACC);

  k_detect<<<1, 256, 0, stream>>>(ei, flag);
  k_wt<<<16, 256, 0, stream>>>(W1, Wt);
  k_hist<<<NB_HIST, 256, 0, stream>>>(ei, flag, ghist);
  k_bucket_scan<<<NBUCK, 256, 0, stream>>>(ghist, gchoff, btot, ubtot);
  k_scan_tot<<<1, 1024, 0, stream>>>(btot, bbase);
  k_scan_tot<<<1, 1024, 0, stream>>>(ubtot, cbase);
  k_bin<<<NB_BIN, 512, 0, stream>>>(ei, flag, bbase, gchoff, dump);
  k_csr<<<NBUCK, 512, 0, stream>>>(dump, bbase, cbase, srcs, startp, cnt, dis);
  k_gemm1<<<NBUCK, 256, 0, stream>>>(x, Wt, dis, hs);
  k_agg<<<(N_NODES + 7) / 8, 256, 0, stream>>>(hs, startp, cnt, srcs, dis, b1, acc);
  k_final<<<NBUCK, 256, 0, stream>>>(acc, linW, linb, out);
}

// Round 8
// 191.845 us; speedup vs baseline: 7.1382x; 1.0838x over previous
//
#include <hip/hip_runtime.h>
#include <hip/hip_fp16.h>
#include <math.h>

#define N_NODES 100000
#define N_EDGES 1600000
#define NBUCK   1563          // ceil(100000/64) buckets of 64 dst nodes
#define NBUCK_P 1568          // padded row length for hist tables
#define NB_HIST 256           // hist blocks (slice 6250)
#define NB_BIN  256           // bin blocks (slice 6250, same rows as hist)

// ws layout (bytes). acc aliases {ghist,gchoff,dump}: dead before k_agg writes.
#define OFF_FLAG   0x0u
#define OFF_BTOT   0x1000u     // int[NBUCK_P]   padded bucket totals
#define OFF_UBTOT  0x3000u     // int[NBUCK_P]   unpadded bucket totals
#define OFF_BBASE  0x5000u     // int[NBUCK+1]   padded scan (dump base)
#define OFF_CBASE  0x7000u     // int[NBUCK+1]   compact scan (srcs base)
#define OFF_DIS    0x9000u     // float[N_NODES]
#define OFF_CNT    0x70000u    // int[N_NODES]
#define OFF_START  0xE0000u    // int[N_NODES]
#define OFF_SRCS   0x150000u   // int[N_EDGES]
#define OFF_HS     0x780000u   // __half[N_NODES*128] (25.6 MB)
#define OFF_WT     0x2100000u  // __half[128*128] fp16 W1^T (32 KB)
#define OFF_GHIST  0x3980000u  // int[NB_HIST*NBUCK_P]  (1.6 MB, ends 0x3B08000)
#define OFF_GCHOFF 0x3B10000u  // int[NB_BIN*NBUCK_P]   (1.6 MB, ends 0x3C98000)
#define OFF_DUMP   0x3CA0000u  // int2[<=2.0M] (16.1 MB, ends ~0x4CC0000)
#define OFF_ACC    0x3980000u  // __half[N_NODES*128] aliases binning scratch

typedef _Float16 half8_t __attribute__((ext_vector_type(8)));
typedef float f32x4_t __attribute__((ext_vector_type(4)));

// ---- edge dtype detect: int64 edge_index has zero high words ----
__global__ void k_detect(const int* __restrict__ p32, int* __restrict__ flag) {
  __shared__ int nz;
  if (threadIdx.x == 0) nz = 0;
  __syncthreads();
  if (p32[2 * threadIdx.x + 1] != 0) atomicAdd(&nz, 1);
  __syncthreads();
  if (threadIdx.x == 0) *flag = (nz == 0) ? 1 : 0;  // 1 => int64 (stride 2)
}

// W1 (f32 [128k][128n]) -> Wt (fp16 [128n][128k]); block b owns k rows [8b,8b+8)
__global__ __launch_bounds__(256) void k_wt(const float* __restrict__ W,
                                            __half* __restrict__ Wt) {
  __shared__ float buf[1024];
  const int t = threadIdx.x;
  const int b = blockIdx.x;
  float4 v = ((const float4*)(W + (size_t)b * 1024))[t];
  *(float4*)&buf[t * 4] = v;
  __syncthreads();
  if (t < 128) {
    union { __half h[8]; int4 v; } u;
#pragma unroll
    for (int k = 0; k < 8; ++k) u.h[k] = __float2half(buf[k * 128 + t]);
    *(int4*)&Wt[(size_t)t * 128 + b * 8] = u.v;
  }
}

// per-block bucket histogram of dst
__global__ __launch_bounds__(256) void k_hist(const int* __restrict__ p32,
                                              const int* __restrict__ flag,
                                              int* __restrict__ G_hist) {
  __shared__ int hist[NBUCK];
  const int t = threadIdx.x;
  for (int i = t; i < NBUCK; i += 256) hist[i] = 0;
  __syncthreads();
  const int base = blockIdx.x * 6250;
  const int s = *flag;
  for (int i = 0; i < 25; ++i) {
    int e = base + i * 256 + t;
    if (e < base + 6250) {
      int c = p32[((size_t)(N_EDGES + e)) << s];
      atomicAdd(&hist[c >> 6], 1);
    }
  }
  __syncthreads();
  for (int i = t; i < NBUCK; i += 256) G_hist[blockIdx.x * NBUCK_P + i] = hist[i];
}

// per bucket: 256 bin-chunk sizes (hist entries), pad to x2, block-wide scan.
__global__ __launch_bounds__(256) void k_bucket_scan(const int* __restrict__ G_hist,
                                                     int* __restrict__ G_choff,
                                                     int* __restrict__ btot,
                                                     int* __restrict__ ubtot) {
  __shared__ int wsp[4], wsu[4];
  const int t = threadIdx.x;
  const int b = blockIdx.x;
  const int c = G_hist[t * NBUCK_P + b];
  const int p = (c + 1) & ~1;
  int sp = p, su = c;
  const int lane = t & 63;
  for (int d = 1; d < 64; d <<= 1) {
    int a = __shfl_up(sp, d), e = __shfl_up(su, d);
    if (lane >= d) { sp += a; su += e; }
  }
  if (lane == 63) { wsp[t >> 6] = sp; wsu[t >> 6] = su; }
  __syncthreads();
  int op = 0, ou = 0;
  for (int w2 = 0; w2 < (t >> 6); ++w2) { op += wsp[w2]; ou += wsu[w2]; }
  G_choff[t * NBUCK_P + b] = op + sp - p;  // exclusive padded offset in bucket
  if (t == 255) { btot[b] = op + sp; ubtot[b] = ou + su; }
}

// scan 1563 totals -> base[0..NBUCK]; block 0: padded->bbase, block 1: unpadded->cbase
__global__ __launch_bounds__(1024) void k_scan_tot2(const int* __restrict__ btot,
                                                    const int* __restrict__ ubtot,
                                                    int* __restrict__ bbase,
                                                    int* __restrict__ cbase) {
  __shared__ int sm[1024];
  const int* tot = blockIdx.x ? ubtot : btot;
  int* base = blockIdx.x ? cbase : bbase;
  const int t = threadIdx.x;
  int a = (2 * t < NBUCK) ? tot[2 * t] : 0;
  int bb = (2 * t + 1 < NBUCK) ? tot[2 * t + 1] : 0;
  int pair = a + bb;
  sm[t] = pair;
  __syncthreads();
  for (int off = 1; off < 1024; off <<= 1) {
    int x = (t >= off) ? sm[t - off] : 0;
    __syncthreads();
    sm[t] += x;
    __syncthreads();
  }
  int S = sm[t];
  if (2 * t <= NBUCK) base[2 * t] = S - pair;
  if (2 * t + 1 <= NBUCK) base[2 * t + 1] = S - bb;
}

// place (src,dst) records into block-private padded chunks; sentinel tails
__global__ __launch_bounds__(512) void k_bin(const int* __restrict__ p32,
                                             const int* __restrict__ flag,
                                             const int* __restrict__ bbase,
                                             const int* __restrict__ G_choff,
                                             int2* __restrict__ dump) {
  __shared__ int gb[NBUCK];
  __shared__ int cur[NBUCK];
  const int t = threadIdx.x;
  const int blk = blockIdx.x;
  for (int i = t; i < NBUCK; i += 512) {
    gb[i] = bbase[i] + G_choff[blk * NBUCK_P + i];
    cur[i] = 0;
  }
  __syncthreads();
  const int base = blk * 6250;
  const int s = *flag;
  for (int i = 0; i < 13; ++i) {
    int e = base + i * 512 + t;
    if (e < base + 6250) {
      int r = p32[((size_t)e) << s];
      int c = p32[((size_t)(N_EDGES + e)) << s];
      int bk = c >> 6;
      int p = atomicAdd(&cur[bk], 1);
      dump[gb[bk] + p] = make_int2(r, c);
    }
  }
  __syncthreads();
  for (int i = t; i < NBUCK; i += 512) {
    int c0 = cur[i];
    if (c0 & 1) dump[gb[i] + c0] = make_int2(0, -1);  // pad to x2
  }
}

// per bucket: dump chunk -> per-node CSR at COMPACT offsets + deg/dis
__global__ __launch_bounds__(512) void k_csr(const int2* __restrict__ dump,
                                             const int* __restrict__ bbase,
                                             const int* __restrict__ cbase,
                                             int* __restrict__ srcs,
                                             int* __restrict__ startp,
                                             int* __restrict__ cnt,
                                             float* __restrict__ dis) {
  __shared__ int cnt_s[64];
  __shared__ int off_s[64];
  __shared__ int cur_s[64];
  __shared__ int stage[3072];
  const int t = threadIdx.x;
  const int b = blockIdx.x;
  if (t < 64) cnt_s[t] = 0;
  __syncthreads();
  const int rb = bbase[b];
  const int m = bbase[b + 1] - rb;
  const int cb = cbase[b];
  for (int j = t; j < m; j += 512) {
    int2 rec = dump[rb + j];
    if (rec.y >= 0) atomicAdd(&cnt_s[rec.y & 63], 1);
  }
  __syncthreads();
  if (t < 64) {
    int v = cnt_s[t];
    int sv = v;
    for (int d = 1; d < 64; d <<= 1) {
      int u = __shfl_up(sv, d);
      if (t >= d) sv += u;
    }
    off_s[t] = sv - v;
    cur_s[t] = sv - v;
  }
  __syncthreads();
  for (int j = t; j < m; j += 512) {
    int2 rec = dump[rb + j];
    if (rec.y >= 0) {
      int p = atomicAdd(&cur_s[rec.y & 63], 1);
      stage[p] = rec.x;
    }
  }
  __syncthreads();
  const int total = off_s[63] + cnt_s[63];
  for (int j = t; j < total; j += 512) srcs[cb + j] = stage[j];
  if (t < 64) {
    int n = (b << 6) + t;
    if (n < N_NODES) {
      cnt[n] = cnt_s[t];
      startp[n] = cb + off_s[t];
      dis[n] = rsqrtf((float)cnt_s[t] + 1.0f);
    }
  }
}

// hs[n] = fp16( dis[n] * (x @ W1)[n] )  via MFMA f16.
__global__ __launch_bounds__(256, 3) void k_gemm1(
    const float* __restrict__ x, const __half* __restrict__ Wt,
    const float* __restrict__ dis, __half* __restrict__ hs) {
  __shared__ _Float16 xt[64 * 136];
  __shared__ _Float16 wt[128 * 136];
  const int t = threadIdx.x;
  const int row0 = blockIdx.x * 64;
#pragma unroll
  for (int i = 0; i < 8; ++i) {
    int lin = i * 256 + t;
    int r = lin >> 5, c4 = lin & 31;
    int gr = row0 + r;
    float4 v = make_float4(0.f, 0.f, 0.f, 0.f);
    if (gr < N_NODES) v = *(const float4*)(x + (size_t)gr * 128 + c4 * 4);
    union { __half2 h2[2]; int2 iv; } u;
    u.h2[0] = __floats2half2_rn(v.x, v.y);
    u.h2[1] = __floats2half2_rn(v.z, v.w);
    *(int2*)&xt[r * 136 + c4 * 4] = u.iv;
  }
#pragma unroll
  for (int i = 0; i < 8; ++i) {
    int lin = i * 256 + t;
    int n = lin >> 4, kb = lin & 15;
    int4 v = *(const int4*)(Wt + (size_t)n * 128 + kb * 8);
    *(int4*)&wt[n * 136 + kb * 8] = v;
  }
  __syncthreads();

  const int w = t >> 6, l = t & 63;
  const int r = l & 15, g = l >> 4;
  const _Float16* ap = &xt[(w * 16 + r) * 136 + g * 8];
  half8_t af[4];
#pragma unroll
  for (int ks = 0; ks < 4; ++ks) af[ks] = *(const half8_t*)&ap[ks * 32];

  const int rbase = row0 + w * 16 + g * 4;
  float dv[4];
#pragma unroll
  for (int j = 0; j < 4; ++j) {
    int rr = rbase + j;
    dv[j] = (rr < N_NODES) ? dis[rr] : 0.f;
  }

#pragma unroll
  for (int ct = 0; ct < 8; ++ct) {
    f32x4_t acc = {0.f, 0.f, 0.f, 0.f};
    const _Float16* bp = &wt[(ct * 16 + r) * 136 + g * 8];
#pragma unroll
    for (int ks = 0; ks < 4; ++ks) {
      half8_t bf = *(const half8_t*)&bp[ks * 32];
      acc = __builtin_amdgcn_mfma_f32_16x16x32_f16(af[ks], bf, acc, 0, 0, 0);
    }
#pragma unroll
    for (int j = 0; j < 4; ++j) {
      int rr = rbase + j;
      if (rr < N_NODES)
        hs[(size_t)rr * 128 + ct * 16 + r] = __float2half(acc[j] * dv[j]);
    }
  }
}

// acc[n] = fp16( dis[n]*(hs[n] + sum_in hs[src]) + b1 )  -- 32 lanes/node, 8x unroll
__global__ __launch_bounds__(256) void k_agg(
    const __half* __restrict__ hs, const int* __restrict__ startp,
    const int* __restrict__ cnt, const int* __restrict__ srcs,
    const float* __restrict__ dis, const float* __restrict__ b1,
    __half* __restrict__ acc) {
  const int t = threadIdx.x;
  const int g = t >> 5, lane = t & 31;
  const int n = blockIdx.x * 8 + g;
  if (n >= N_NODES) return;
  float4 sum;
  {
    uint2 raw = *(const uint2*)(hs + (size_t)n * 128 + lane * 4);  // self-loop
    float2 fa = __half22float2(*(__half2*)&raw.x);
    float2 fb = __half22float2(*(__half2*)&raw.y);
    sum = make_float4(fa.x, fa.y, fb.x, fb.y);
  }
  const int s0 = startp[n];
  const int e0 = s0 + cnt[n];
  int j = s0;
  for (; j + 8 <= e0; j += 8) {
    uint2 r[8];
#pragma unroll
    for (int q = 0; q < 8; ++q) {
      int src = srcs[j + q];
      r[q] = *(const uint2*)(hs + (size_t)src * 128 + lane * 4);
    }
#pragma unroll
    for (int q = 0; q < 8; ++q) {
      float2 a = __half22float2(*(__half2*)&r[q].x);
      float2 b = __half22float2(*(__half2*)&r[q].y);
      sum.x += a.x; sum.y += a.y; sum.z += b.x; sum.w += b.y;
    }
  }
  if (j + 4 <= e0) {
    uint2 r[4];
#pragma unroll
    for (int q = 0; q < 4; ++q) {
      int src = srcs[j + q];
      r[q] = *(const uint2*)(hs + (size_t)src * 128 + lane * 4);
    }
#pragma unroll
    for (int q = 0; q < 4; ++q) {
      float2 a = __half22float2(*(__half2*)&r[q].x);
      float2 b = __half22float2(*(__half2*)&r[q].y);
      sum.x += a.x; sum.y += a.y; sum.z += b.x; sum.w += b.y;
    }
    j += 4;
  }
  for (; j < e0; ++j) {
    int src = srcs[j];
    uint2 r0 = *(const uint2*)(hs + (size_t)src * 128 + lane * 4);
    float2 a0 = __half22float2(*(__half2*)&r0.x), b0 = __half22float2(*(__half2*)&r0.y);
    sum.x += a0.x; sum.y += a0.y; sum.z += b0.x; sum.w += b0.y;
  }
  float d = dis[n];
  float4 b = *(const float4*)(b1 + lane * 4);
  union { __half2 h[2]; unsigned long long v; } u;
  u.h[0] = __floats2half2_rn(fmaf(d, sum.x, b.x), fmaf(d, sum.y, b.y));
  u.h[1] = __floats2half2_rn(fmaf(d, sum.z, b.z), fmaf(d, sum.w, b.w));
  __builtin_nontemporal_store(
      u.v, (unsigned long long*)(acc + (size_t)n * 128 + lane * 4));
}

// out[n] = log_softmax(relu(acc[n]) @ linW + linb)   -- 4 lanes/node
__global__ __launch_bounds__(256) void k_final(
    const __half* __restrict__ acc, const float* __restrict__ linW,
    const float* __restrict__ linb, float* __restrict__ out) {
  __shared__ float vs[64][132];
  __shared__ float wl[128 * 40];
  __shared__ float lb[40];
  const int t = threadIdx.x;
  const int n0 = blockIdx.x * 64;
#pragma unroll
  for (int i = 0; i < 5; ++i) {
    int lin = i * 256 + t;
    ((float4*)wl)[lin] = ((const float4*)linW)[lin];
  }
  if (t < 40) lb[t] = linb[t];
#pragma unroll
  for (int i = 0; i < 4; ++i) {
    int lin = i * 256 + t;
    int r = lin >> 4, c8 = lin & 15;
    int n = n0 + r;
    float vals[8];
#pragma unroll
    for (int q = 0; q < 8; ++q) vals[q] = 0.f;
    if (n < N_NODES) {
      uint4 raw = *(const uint4*)(acc + (size_t)n * 128 + c8 * 8);
      const __half2* hp = (const __half2*)&raw;
#pragma unroll
      for (int q = 0; q < 4; ++q) {
        float2 f = __half22float2(hp[q]);
        vals[2 * q]     = fmaxf(f.x, 0.f);
        vals[2 * q + 1] = fmaxf(f.y, 0.f);
      }
    }
#pragma unroll
    for (int q = 0; q < 8; ++q) vs[r][c8 * 8 + q] = vals[q];
  }
  __syncthreads();
  const int nl = t >> 2, l4 = t & 3;
  const int n = n0 + nl;
  if (n >= N_NODES) return;
  float lg[10];
#pragma unroll
  for (int j = 0; j < 10; ++j) lg[j] = lb[l4 * 10 + j];
  for (int k = 0; k < 128; ++k) {
    float vk = vs[nl][k];
#pragma unroll
    for (int j = 0; j < 10; ++j) lg[j] = fmaf(vk, wl[k * 40 + l4 * 10 + j], lg[j]);
  }
  float m = lg[0];
#pragma unroll
  for (int j = 1; j < 10; ++j) m = fmaxf(m, lg[j]);
  m = fmaxf(m, __shfl_xor(m, 1));
  m = fmaxf(m, __shfl_xor(m, 2));
  float s = 0.f;
#pragma unroll
  for (int j = 0; j < 10; ++j) s += expf(lg[j] - m);
  s += __shfl_xor(s, 1);
  s += __shfl_xor(s, 2);
  float lse = m + logf(s);
#pragma unroll
  for (int j = 0; j < 10; ++j) out[(size_t)n * 40 + l4 * 10 + j] = lg[j] - lse;
}

extern "C" void kernel_launch(void* const* d_in, const int* in_sizes, int n_in,
                              void* d_out, int out_size, void* d_ws, size_t ws_size,
                              hipStream_t stream) {
  const float* x    = (const float*)d_in[0];
  const int*   ei   = (const int*)d_in[1];
  const float* W1   = (const float*)d_in[2];
  const float* b1   = (const float*)d_in[3];
  const float* linW = (const float*)d_in[4];
  const float* linb = (const float*)d_in[5];
  float* out = (float*)d_out;
  char* ws = (char*)d_ws;

  int*    flag   = (int*)(ws + OFF_FLAG);
  int*    btot   = (int*)(ws + OFF_BTOT);
  int*    ubtot  = (int*)(ws + OFF_UBTOT);
  int*    bbase  = (int*)(ws + OFF_BBASE);
  int*    cbase  = (int*)(ws + OFF_CBASE);
  float*  dis    = (float*)(ws + OFF_DIS);
  int*    cnt    = (int*)(ws + OFF_CNT);
  int*    startp = (int*)(ws + OFF_START);
  int*    srcs   = (int*)(ws + OFF_SRCS);
  __half* hs     = (__half*)(ws + OFF_HS);
  __half* Wt     = (__half*)(ws + OFF_WT);
  int*    ghist  = (int*)(ws + OFF_GHIST);
  int*    gchoff = (int*)(ws + OFF_GCHOFF);
  int2*   dump   = (int2*)(ws + OFF_DUMP);
  __half* acc    = (__half*)(ws + OFF_ACC);

  k_detect<<<1, 256, 0, stream>>>(ei, flag);
  k_wt<<<16, 256, 0, stream>>>(W1, Wt);
  k_hist<<<NB_HIST, 256, 0, stream>>>(ei, flag, ghist);
  k_bucket_scan<<<NBUCK, 256, 0, stream>>>(ghist, gchoff, btot, ubtot);
  k_scan_tot2<<<2, 1024, 0, stream>>>(btot, ubtot, bbase, cbase);
  k_bin<<<NB_BIN, 512, 0, stream>>>(ei, flag, bbase, gchoff, dump);
  k_csr<<<NBUCK, 512, 0, stream>>>(dump, bbase, cbase, srcs, startp, cnt, dis);
  k_gemm1<<<NBUCK, 256, 0, stream>>>(x, Wt, dis, hs);
  k_agg<<<(N_NODES + 7) / 8, 256, 0, stream>>>(hs, startp, cnt, srcs, dis, b1, acc);
  k_final<<<NBUCK, 256, 0, stream>>>(acc, linW, linb, out);
}